// Round 6
// baseline (697.070 us; speedup 1.0000x reference)
//
#include <hip/hip_runtime.h>
#include <math.h>

#define N_NODESC 50000
#define NPAD 50048              // 782 * 64, padded for unmasked frag loads
#define N_EDGESC 800000
#define N_GRAPHSC 64
#define IN_DIMC 128
#define HIDC 256
#define N_LAYERSC 4
#define EPSV 1e-12f

#define SCAN_BLK 196  // ceil(50000/256)

typedef __attribute__((ext_vector_type(8))) short short8;
typedef __attribute__((ext_vector_type(4))) float floatx4;

__device__ __forceinline__ unsigned short f2b(float f) {
    union { float f; unsigned u; } v; v.f = f;
    unsigned r = v.u + 0x7FFFu + ((v.u >> 16) & 1u);
    return (unsigned short)(r >> 16);
}
__device__ __forceinline__ float blo(unsigned u) { return __uint_as_float(u << 16); }
__device__ __forceinline__ float bhi(unsigned u) { return __uint_as_float(u & 0xFFFF0000u); }
__device__ __forceinline__ unsigned pkb(float a, float b) {
    return (unsigned)f2b(a) | ((unsigned)f2b(b) << 16);
}
__device__ __forceinline__ float b2f(unsigned short s) {
    return __uint_as_float((unsigned)s << 16);
}

// A-fragment-order index for element (row, k) with 8 k-chunks per 256-k matrix:
// ((row>>4)*8 + (k>>5))*512 + (((k>>3)&3)*16 + (row&15))*8 + (k&7)

// ---------------- degree count ----------------
__global__ void k_count(const int* __restrict__ dst, int* __restrict__ deg) {
    int e = blockIdx.x * blockDim.x + threadIdx.x;
    if (e < N_EDGESC) atomicAdd(&deg[dst[e]], 1);
}

// ---------------- graph boundaries via binary search (gid sorted) ----------------
__global__ __launch_bounds__(128) void k_gbounds(const int* __restrict__ gid,
        int* __restrict__ gstart) {
    int g = threadIdx.x;
    if (g > N_GRAPHSC) return;
    int lo = 0, hi = N_NODESC;
    while (lo < hi) {
        int mid = (lo + hi) >> 1;
        if (gid[mid] < g) lo = mid + 1; else hi = mid;
    }
    gstart[g] = lo;
}

// ---------------- hierarchical scan ----------------
__global__ __launch_bounds__(256) void k_scanA(const int* __restrict__ deg,
        int* __restrict__ bsum) {
    __shared__ int s[256];
    int t = threadIdx.x;
    int i = blockIdx.x * 256 + t;
    s[t] = (i < N_NODESC) ? deg[i] : 0;
    __syncthreads();
    for (int d = 128; d > 0; d >>= 1) {
        if (t < d) s[t] += s[t + d];
        __syncthreads();
    }
    if (t == 0) bsum[blockIdx.x] = s[0];
}

__global__ __launch_bounds__(256) void k_scanB(const int* __restrict__ bsum,
        int* __restrict__ boff) {
    __shared__ int s[256];
    int t = threadIdx.x;
    int v = (t < SCAN_BLK) ? bsum[t] : 0;
    s[t] = v;
    __syncthreads();
    for (int d = 1; d < 256; d <<= 1) {
        int u = (t >= d) ? s[t - d] : 0;
        __syncthreads();
        s[t] += u;
        __syncthreads();
    }
    if (t < SCAN_BLK) boff[t] = s[t] - v;
}

__global__ __launch_bounds__(256) void k_scanC(const int* __restrict__ deg,
        const int* __restrict__ boff, int* __restrict__ offs, int* __restrict__ cursor) {
    __shared__ int s[256];
    int t = threadIdx.x;
    int i = blockIdx.x * 256 + t;
    int v = (i < N_NODESC) ? deg[i] : 0;
    s[t] = v;
    __syncthreads();
    for (int d = 1; d < 256; d <<= 1) {
        int u = (t >= d) ? s[t - d] : 0;
        __syncthreads();
        s[t] += u;
        __syncthreads();
    }
    int excl = s[t] - v + boff[blockIdx.x];
    if (i < N_NODESC) {
        offs[i] = excl;
        cursor[i] = excl;
        if (i == N_NODESC - 1) offs[N_NODESC] = excl + v;
    }
}

// ---------------- scatter edges into CSR buckets ----------------
__global__ void k_scatter(const int* __restrict__ src, const int* __restrict__ dst,
        int* __restrict__ cursor, int* __restrict__ esrc) {
    int e = blockIdx.x * blockDim.x + threadIdx.x;
    if (e < N_EDGESC) {
        int d = dst[e];
        int pos = atomicAdd(&cursor[d], 1);
        esrc[pos] = src[e];
    }
}

// ---------------- weight convert + swizzle to MFMA B-fragment order ----------------
__global__ __launch_bounds__(256) void k_wconv(const float* __restrict__ Wemb,
        const float* __restrict__ Ws, unsigned short* __restrict__ wsw) {
    int idx = blockIdx.x * 256 + threadIdx.x;
    const int EMB = IN_DIMC * HIDC;           // 32768
    const int LYR = 2 * HIDC * HIDC;          // 131072
    if (idx >= EMB + N_LAYERSC * LYR) return;
    float val; int k, n; unsigned short* basep;
    if (idx < EMB) {
        k = idx >> 8; n = idx & 255;
        val = Wemb[idx];
        basep = wsw;
    } else {
        int r = idx - EMB;
        int l = r >> 17;
        int r2 = r & (LYR - 1);
        k = r2 >> 8; n = r2 & 255;
        val = Ws[r];
        basep = wsw + EMB + l * LYR;
    }
    int off = (((k >> 5) * 16 + (n >> 4)) * 64 + ((((k >> 3) & 3) << 4) | (n & 15))) * 8 + (k & 7);
    basep[off] = f2b(val);
}

// ---------------- per-node mean aggregation: gather row-major xb, write frag-order cs --------
__global__ __launch_bounds__(256) void k_aggregate(const unsigned short* __restrict__ xb,
        const int* __restrict__ offs, const int* __restrict__ esrc,
        unsigned short* __restrict__ cs) {
    int gidx = blockIdx.x * 256 + threadIdx.x;
    int node = gidx >> 5;
    int lane = threadIdx.x & 31;
    if (node >= N_NODESC) return;
    int beg = offs[node], end = offs[node + 1];
    float a[8];
    #pragma unroll
    for (int j = 0; j < 8; j++) a[j] = 0.f;
    size_t loff = (size_t)lane * 8;
    int e = beg;
    for (; e + 8 <= end; e += 8) {
        int sidx[8];
        #pragma unroll
        for (int j = 0; j < 8; j++) sidx[j] = esrc[e + j];
        uint4 v[8];
        #pragma unroll
        for (int j = 0; j < 8; j++)
            v[j] = *(const uint4*)(xb + (size_t)sidx[j] * HIDC + loff);
        #pragma unroll
        for (int j = 0; j < 8; j++) {
            a[0] += blo(v[j].x); a[1] += bhi(v[j].x);
            a[2] += blo(v[j].y); a[3] += bhi(v[j].y);
            a[4] += blo(v[j].z); a[5] += bhi(v[j].z);
            a[6] += blo(v[j].w); a[7] += bhi(v[j].w);
        }
    }
    if (e + 4 <= end) {
        int sidx[4];
        #pragma unroll
        for (int j = 0; j < 4; j++) sidx[j] = esrc[e + j];
        uint4 v[4];
        #pragma unroll
        for (int j = 0; j < 4; j++)
            v[j] = *(const uint4*)(xb + (size_t)sidx[j] * HIDC + loff);
        #pragma unroll
        for (int j = 0; j < 4; j++) {
            a[0] += blo(v[j].x); a[1] += bhi(v[j].x);
            a[2] += blo(v[j].y); a[3] += bhi(v[j].y);
            a[4] += blo(v[j].z); a[5] += bhi(v[j].z);
            a[6] += blo(v[j].w); a[7] += bhi(v[j].w);
        }
        e += 4;
    }
    for (; e < end; e++) {
        uint4 v = *(const uint4*)(xb + (size_t)esrc[e] * HIDC + loff);
        a[0] += blo(v.x); a[1] += bhi(v.x);
        a[2] += blo(v.y); a[3] += bhi(v.y);
        a[4] += blo(v.z); a[5] += bhi(v.z);
        a[6] += blo(v.w); a[7] += bhi(v.w);
    }
    float w = 1.0f / (float)max(end - beg, 1);
    uint4 o;
    o.x = pkb(a[0] * w, a[1] * w);
    o.y = pkb(a[2] * w, a[3] * w);
    o.z = pkb(a[4] * w, a[5] * w);
    o.w = pkb(a[6] * w, a[7] * w);
    // frag-order write: rgb=node>>4, m=node&15, kc=lane>>2, kq=lane&3
    *(uint4*)(cs + ((size_t)((node >> 4) * 8 + (lane >> 2)) * 64
                    + (size_t)((lane & 3) * 16 + (node & 15))) * 8) = o;
}

// ---------------- layer GEMM: barrier-free K-loop, direct frag loads ----------------
// A rows [64b,64b+64): x-frags from xs (k<256), c-frags from cs (k>=256), B from wsw.
// Epilogue: bias -> row L2-norm -> relu -> residual; writes xb (row-major) + xs (frag).
__global__ __launch_bounds__(256) void k_lgemm(const unsigned short* __restrict__ xs,
        const unsigned short* __restrict__ cs, const unsigned short* __restrict__ wb,
        const float* __restrict__ bias, unsigned short* __restrict__ xb) {
    __shared__ float rs[64];
    int tid = threadIdx.x;
    int w = tid >> 6;
    int lane = tid & 63;
    int quad = lane >> 4;
    int l15 = lane & 15;
    int row0 = blockIdx.x * 64;
    const unsigned short* xsb = xs + (size_t)blockIdx.x * 16384;
    const unsigned short* csb = cs + (size_t)blockIdx.x * 16384;

    floatx4 acc[4][4];
    #pragma unroll
    for (int mt = 0; mt < 4; mt++)
        #pragma unroll
        for (int n = 0; n < 4; n++)
            acc[mt][n] = (floatx4){0.f, 0.f, 0.f, 0.f};

    short8 aA[4], bA[4], aB[4], bB[4];
    auto loadA = [&](int ks, short8* a) {
        const unsigned short* base = (ks < 8) ? (xsb + ks * 512) : (csb + (ks - 8) * 512);
        #pragma unroll
        for (int mt = 0; mt < 4; mt++)
            a[mt] = *(const short8*)(base + mt * 4096 + lane * 8);
    };
    auto loadB = [&](int ks, short8* b) {
        const unsigned short* wp = wb + ((size_t)(ks * 16 + w * 4) * 64 + lane) * 8;
        #pragma unroll
        for (int n = 0; n < 4; n++)
            b[n] = *(const short8*)(wp + n * 512);
    };
    auto domfma = [&](short8* a, short8* b) {
        #pragma unroll
        for (int mt = 0; mt < 4; mt++)
            #pragma unroll
            for (int n = 0; n < 4; n++)
                acc[mt][n] = __builtin_amdgcn_mfma_f32_16x16x32_bf16(a[mt], b[n], acc[mt][n], 0, 0, 0);
    };

    loadA(0, aA); loadB(0, bA);
    #pragma unroll
    for (int ks = 0; ks < 16; ks += 2) {
        loadA(ks + 1, aB); loadB(ks + 1, bB);
        domfma(aA, bA);
        if (ks + 2 < 16) { loadA(ks + 2, aA); loadB(ks + 2, bA); }
        domfma(aB, bB);
    }

    // bias
    float bv[4];
    #pragma unroll
    for (int n = 0; n < 4; n++) bv[n] = bias[(w * 4 + n) * 16 + l15];
    #pragma unroll
    for (int mt = 0; mt < 4; mt++)
        #pragma unroll
        for (int n = 0; n < 4; n++)
            #pragma unroll
            for (int r = 0; r < 4; r++)
                acc[mt][n][r] += bv[n];

    // row sum-of-squares across block
    __syncthreads();
    if (tid < 64) rs[tid] = 0.f;
    __syncthreads();
    #pragma unroll
    for (int mt = 0; mt < 4; mt++) {
        #pragma unroll
        for (int r = 0; r < 4; r++) {
            float p = acc[mt][0][r] * acc[mt][0][r] + acc[mt][1][r] * acc[mt][1][r]
                    + acc[mt][2][r] * acc[mt][2][r] + acc[mt][3][r] * acc[mt][3][r];
            p += __shfl_xor(p, 1);
            p += __shfl_xor(p, 2);
            p += __shfl_xor(p, 4);
            p += __shfl_xor(p, 8);
            if (l15 == 0) atomicAdd(&rs[mt * 16 + quad * 4 + r], p);
        }
    }
    __syncthreads();

    unsigned short* xsw = (unsigned short*)xs;  // in-place frag update (rows owned by block)
    #pragma unroll
    for (int mt = 0; mt < 4; mt++) {
        int rgb = blockIdx.x * 4 + mt;
        #pragma unroll
        for (int r = 0; r < 4; r++) {
            int row = row0 + mt * 16 + quad * 4 + r;
            int m = quad * 4 + r;
            if (row < N_NODESC) {
                float inv = 1.0f / fmaxf(sqrtf(rs[mt * 16 + quad * 4 + r]), EPSV);
                #pragma unroll
                for (int n = 0; n < 4; n++) {
                    int col = w * 64 + n * 16 + l15;
                    size_t idx = (size_t)row * HIDC + col;
                    float xo = b2f(xb[idx]);
                    float v = fmaxf(acc[mt][n][r] * inv, 0.f);
                    float nv = xo + v;
                    unsigned short nb = f2b(nv);
                    xb[idx] = nb;
                    int kc = col >> 5, kq = (col >> 3) & 3, j = col & 7;
                    xsw[((size_t)(rgb * 8 + kc) * 64 + kq * 16 + m) * 8 + j] = nb;
                }
            }
        }
    }
}

// ---------------- embed GEMM (fp32 A via LDS stage): writes xb + xs ----------------
__global__ __launch_bounds__(256) void k_egemm(const float* __restrict__ h,
        const unsigned short* __restrict__ wsw, const float* __restrict__ bias,
        unsigned short* __restrict__ xb, unsigned short* __restrict__ xs) {
    __shared__ unsigned short As[4 * 64 * 8];
    int tid = threadIdx.x;
    int w = tid >> 6;
    int lane = tid & 63;
    int quad = lane >> 4;
    int l15 = lane & 15;
    int row0 = blockIdx.x * 64;

    floatx4 acc[4][4];
    #pragma unroll
    for (int mt = 0; mt < 4; mt++)
        #pragma unroll
        for (int n = 0; n < 4; n++)
            acc[mt][n] = (floatx4){0.f, 0.f, 0.f, 0.f};

    int sm = tid >> 2;
    int sq = tid & 3;
    int srow = row0 + sm;
    int soff = ((sm >> 4) * 64 + (sq << 4) + (sm & 15)) * 8;

    for (int ks = 0; ks < 4; ks++) {
        __syncthreads();
        int k = ks * 32 + sq * 8;
        uint4 av = make_uint4(0, 0, 0, 0);
        if (srow < N_NODESC) {
            const float* p = h + (size_t)srow * IN_DIMC + k;
            float4 f0 = *(const float4*)p;
            float4 f1 = *(const float4*)(p + 4);
            av.x = pkb(f0.x, f0.y); av.y = pkb(f0.z, f0.w);
            av.z = pkb(f1.x, f1.y); av.w = pkb(f1.z, f1.w);
        }
        *(uint4*)&As[soff] = av;
        __syncthreads();

        short8 afr[4], bfr[4];
        #pragma unroll
        for (int mt = 0; mt < 4; mt++)
            afr[mt] = *(const short8*)&As[(mt * 64 + lane) * 8];
        const unsigned short* wp = wsw + ((size_t)(ks * 16 + w * 4) * 64 + lane) * 8;
        #pragma unroll
        for (int n = 0; n < 4; n++)
            bfr[n] = *(const short8*)(wp + n * 512);
        #pragma unroll
        for (int mt = 0; mt < 4; mt++)
            #pragma unroll
            for (int n = 0; n < 4; n++)
                acc[mt][n] = __builtin_amdgcn_mfma_f32_16x16x32_bf16(afr[mt], bfr[n], acc[mt][n], 0, 0, 0);
    }

    float bv[4];
    #pragma unroll
    for (int n = 0; n < 4; n++) bv[n] = bias[(w * 4 + n) * 16 + l15];
    #pragma unroll
    for (int mt = 0; mt < 4; mt++) {
        int rgb = blockIdx.x * 4 + mt;
        #pragma unroll
        for (int r = 0; r < 4; r++) {
            int row = row0 + mt * 16 + quad * 4 + r;
            int m = quad * 4 + r;
            if (row < N_NODESC) {
                #pragma unroll
                for (int n = 0; n < 4; n++) {
                    int col = w * 64 + n * 16 + l15;
                    unsigned short nb = f2b(acc[mt][n][r] + bv[n]);
                    xb[(size_t)row * HIDC + col] = nb;
                    int kc = col >> 5, kq = (col >> 3) & 3, j = col & 7;
                    xs[((size_t)(rgb * 8 + kc) * 64 + kq * 16 + m) * 8 + j] = nb;
                }
            }
        }
    }
}

// ---------------- graph mean-pool: 1 block per (graph, 64-col quarter) ----------------
__global__ __launch_bounds__(256) void k_pool(const unsigned short* __restrict__ xb,
        const int* __restrict__ gstart, float* __restrict__ hg) {
    __shared__ float red[256][8];
    int g = blockIdx.x >> 2;
    int cq = blockIdx.x & 3;
    int t = threadIdx.x;
    int cchunk = t & 7;
    int rgrp = t >> 3;
    int col0 = cq * 64 + cchunk * 8;
    int beg = gstart[g], end = gstart[g + 1];
    float a[8];
    #pragma unroll
    for (int j = 0; j < 8; j++) a[j] = 0.f;
    for (int r = beg + rgrp; r < end; r += 32) {
        uint4 v = *(const uint4*)(xb + (size_t)r * HIDC + col0);
        a[0] += blo(v.x); a[1] += bhi(v.x);
        a[2] += blo(v.y); a[3] += bhi(v.y);
        a[4] += blo(v.z); a[5] += bhi(v.z);
        a[6] += blo(v.w); a[7] += bhi(v.w);
    }
    #pragma unroll
    for (int j = 0; j < 8; j++) red[t][j] = a[j];
    __syncthreads();
    for (int d = 16; d >= 1; d >>= 1) {
        if (rgrp < d) {
            #pragma unroll
            for (int j = 0; j < 8; j++) red[t][j] += red[t + d * 8][j];
        }
        __syncthreads();
    }
    if (rgrp == 0) {
        float inv = 1.0f / (float)max(end - beg, 1);
        #pragma unroll
        for (int j = 0; j < 8; j++)
            hg[g * HIDC + col0 + j] = red[t][j] * inv;
    }
}

// ---------------- readout ----------------
__global__ __launch_bounds__(256) void k_readout(const float* __restrict__ hg,
        const float* __restrict__ ppos, const float* __restrict__ pneg,
        const float* __restrict__ wfc, float* __restrict__ out) {
    __shared__ float red[256];
    __shared__ float ss[10];
    int t = threadIdx.x;
    int g = blockIdx.x;
    float hgv = hg[g * HIDC + t];
    for (int p = 0; p < 10; p++) {
        const float* P = (p < 5) ? (ppos + p * HIDC) : (pneg + (p - 5) * HIDC);
        float d = hgv - P[t];
        red[t] = d * d;
        __syncthreads();
        for (int s2 = 128; s2 > 0; s2 >>= 1) {
            if (t < s2) red[t] += red[t + s2];
            __syncthreads();
        }
        if (t == 0) {
            float dd = red[0];
            ss[p] = logf((dd + 1.0f) / (dd + EPSV));
        }
        __syncthreads();
    }
    if (t == 0) {
        float y = 0.f;
        #pragma unroll
        for (int p = 0; p < 10; p++) y += ss[p] * wfc[p];
        out[g] = 1.0f / (1.0f + expf(-y));
    }
}

extern "C" void kernel_launch(void* const* d_in, const int* in_sizes, int n_in,
                              void* d_out, int out_size, void* d_ws, size_t ws_size,
                              hipStream_t stream) {
    const float* h    = (const float*)d_in[0];
    const int*   src  = (const int*)d_in[1];
    const int*   dst  = (const int*)d_in[2];
    const int*   gid  = (const int*)d_in[3];
    const float* Wemb = (const float*)d_in[4];
    const float* bemb = (const float*)d_in[5];
    const float* Ws   = (const float*)d_in[6];
    const float* bs   = (const float*)d_in[7];
    const float* ppos = (const float*)d_in[8];
    const float* pneg = (const float*)d_in[9];
    const float* wfc  = (const float*)d_in[10];
    float* out = (float*)d_out;

    char* ws = (char*)d_ws;
    size_t off = 0;
    auto alloc = [&](size_t bytes) {
        void* p = ws + off;
        off += (bytes + 255) & ~(size_t)255;
        return p;
    };
    unsigned short* xb  = (unsigned short*)alloc((size_t)NPAD * HIDC * 2);  // row-major
    unsigned short* xs  = (unsigned short*)alloc((size_t)NPAD * HIDC * 2);  // frag-order
    unsigned short* cs  = (unsigned short*)alloc((size_t)NPAD * HIDC * 2);  // frag-order
    unsigned short* wsw = (unsigned short*)alloc((size_t)(IN_DIMC * HIDC + N_LAYERSC * 2 * HIDC * HIDC) * 2);
    int*   deg    = (int*)alloc((size_t)N_NODESC * 4);
    int*   offs   = (int*)alloc((size_t)(N_NODESC + 1) * 4);
    int*   cursor = (int*)alloc((size_t)N_NODESC * 4);
    int*   esrc   = (int*)alloc((size_t)N_EDGESC * 4);
    int*   bsum   = (int*)alloc((size_t)SCAN_BLK * 4);
    int*   boff   = (int*)alloc((size_t)SCAN_BLK * 4);
    int*   gstart = (int*)alloc((size_t)(N_GRAPHSC + 1) * 4);
    float* hg     = (float*)alloc((size_t)N_GRAPHSC * HIDC * 4);
    (void)ws_size; (void)in_sizes; (void)n_in; (void)out_size;

    hipMemsetAsync(deg, 0, (size_t)N_NODESC * 4, stream);

    const int WTOT = IN_DIMC * HIDC + N_LAYERSC * 2 * HIDC * HIDC; // 557056
    k_wconv<<<(WTOT + 255) / 256, 256, 0, stream>>>(Wemb, Ws, wsw);
    k_count<<<(N_EDGESC + 255) / 256, 256, 0, stream>>>(dst, deg);
    k_gbounds<<<1, 128, 0, stream>>>(gid, gstart);
    k_scanA<<<SCAN_BLK, 256, 0, stream>>>(deg, bsum);
    k_scanB<<<1, 256, 0, stream>>>(bsum, boff);
    k_scanC<<<SCAN_BLK, 256, 0, stream>>>(deg, boff, offs, cursor);
    k_scatter<<<(N_EDGESC + 255) / 256, 256, 0, stream>>>(src, dst, cursor, esrc);

    const int GBLK = NPAD / 64; // 782
    k_egemm<<<GBLK, 256, 0, stream>>>(h, wsw, bemb, xb, xs);

    for (int l = 0; l < N_LAYERSC; l++) {
        k_aggregate<<<(N_NODESC * 32 + 255) / 256, 256, 0, stream>>>(xb, offs, esrc, cs);
        k_lgemm<<<GBLK, 256, 0, stream>>>(
            xs, cs,
            wsw + IN_DIMC * HIDC + (size_t)l * 2 * HIDC * HIDC,
            bs + (size_t)l * HIDC, xb);
    }
    k_pool<<<N_GRAPHSC * 4, 256, 0, stream>>>(xb, gstart, hg);
    k_readout<<<N_GRAPHSC, 256, 0, stream>>>(hg, ppos, pneg, wfc, out);
}

// Round 7
// 644.290 us; speedup vs baseline: 1.0819x; 1.0819x over previous
//
#include <hip/hip_runtime.h>
#include <math.h>

#define N_NODESC 50000
#define NPAD 50048              // 1564 * 32
#define N_EDGESC 800000
#define N_GRAPHSC 64
#define IN_DIMC 128
#define HIDC 256
#define N_LAYERSC 4
#define EPSV 1e-12f

#define SCAN_BLK 196  // ceil(50000/256)

typedef __attribute__((ext_vector_type(8))) short short8;
typedef __attribute__((ext_vector_type(4))) float floatx4;

__device__ __forceinline__ unsigned short f2b(float f) {
    union { float f; unsigned u; } v; v.f = f;
    unsigned r = v.u + 0x7FFFu + ((v.u >> 16) & 1u);
    return (unsigned short)(r >> 16);
}
__device__ __forceinline__ float blo(unsigned u) { return __uint_as_float(u << 16); }
__device__ __forceinline__ float bhi(unsigned u) { return __uint_as_float(u & 0xFFFF0000u); }
__device__ __forceinline__ unsigned pkb(float a, float b) {
    return (unsigned)f2b(a) | ((unsigned)f2b(b) << 16);
}
__device__ __forceinline__ float b2f(unsigned short s) {
    return __uint_as_float((unsigned)s << 16);
}

// ---------------- degree count ----------------
__global__ void k_count(const int* __restrict__ dst, int* __restrict__ deg) {
    int e = blockIdx.x * blockDim.x + threadIdx.x;
    if (e < N_EDGESC) atomicAdd(&deg[dst[e]], 1);
}

// ---------------- graph boundaries via binary search (gid sorted) ----------------
__global__ __launch_bounds__(128) void k_gbounds(const int* __restrict__ gid,
        int* __restrict__ gstart) {
    int g = threadIdx.x;
    if (g > N_GRAPHSC) return;
    int lo = 0, hi = N_NODESC;
    while (lo < hi) {
        int mid = (lo + hi) >> 1;
        if (gid[mid] < g) lo = mid + 1; else hi = mid;
    }
    gstart[g] = lo;
}

// ---------------- hierarchical scan ----------------
__global__ __launch_bounds__(256) void k_scanA(const int* __restrict__ deg,
        int* __restrict__ bsum) {
    __shared__ int s[256];
    int t = threadIdx.x;
    int i = blockIdx.x * 256 + t;
    s[t] = (i < N_NODESC) ? deg[i] : 0;
    __syncthreads();
    for (int d = 128; d > 0; d >>= 1) {
        if (t < d) s[t] += s[t + d];
        __syncthreads();
    }
    if (t == 0) bsum[blockIdx.x] = s[0];
}

__global__ __launch_bounds__(256) void k_scanB(const int* __restrict__ bsum,
        int* __restrict__ boff) {
    __shared__ int s[256];
    int t = threadIdx.x;
    int v = (t < SCAN_BLK) ? bsum[t] : 0;
    s[t] = v;
    __syncthreads();
    for (int d = 1; d < 256; d <<= 1) {
        int u = (t >= d) ? s[t - d] : 0;
        __syncthreads();
        s[t] += u;
        __syncthreads();
    }
    if (t < SCAN_BLK) boff[t] = s[t] - v;
}

__global__ __launch_bounds__(256) void k_scanC(const int* __restrict__ deg,
        const int* __restrict__ boff, int* __restrict__ offs, int* __restrict__ cursor) {
    __shared__ int s[256];
    int t = threadIdx.x;
    int i = blockIdx.x * 256 + t;
    int v = (i < N_NODESC) ? deg[i] : 0;
    s[t] = v;
    __syncthreads();
    for (int d = 1; d < 256; d <<= 1) {
        int u = (t >= d) ? s[t - d] : 0;
        __syncthreads();
        s[t] += u;
        __syncthreads();
    }
    int excl = s[t] - v + boff[blockIdx.x];
    if (i < N_NODESC) {
        offs[i] = excl;
        cursor[i] = excl;
        if (i == N_NODESC - 1) offs[N_NODESC] = excl + v;
    }
}

// ---------------- scatter edges into CSR buckets ----------------
__global__ void k_scatter(const int* __restrict__ src, const int* __restrict__ dst,
        int* __restrict__ cursor, int* __restrict__ esrc) {
    int e = blockIdx.x * blockDim.x + threadIdx.x;
    if (e < N_EDGESC) {
        int d = dst[e];
        int pos = atomicAdd(&cursor[d], 1);
        esrc[pos] = src[e];
    }
}

// ---------------- weight convert + swizzle to MFMA B-fragment order ----------------
__global__ __launch_bounds__(256) void k_wconv(const float* __restrict__ Wemb,
        const float* __restrict__ Ws, unsigned short* __restrict__ wsw) {
    int idx = blockIdx.x * 256 + threadIdx.x;
    const int EMB = IN_DIMC * HIDC;           // 32768
    const int LYR = 2 * HIDC * HIDC;          // 131072
    if (idx >= EMB + N_LAYERSC * LYR) return;
    float val; int k, n; unsigned short* basep;
    if (idx < EMB) {
        k = idx >> 8; n = idx & 255;
        val = Wemb[idx];
        basep = wsw;
    } else {
        int r = idx - EMB;
        int l = r >> 17;
        int r2 = r & (LYR - 1);
        k = r2 >> 8; n = r2 & 255;
        val = Ws[r];
        basep = wsw + EMB + l * LYR;
    }
    int off = (((k >> 5) * 16 + (n >> 4)) * 64 + ((((k >> 3) & 3) << 4) | (n & 15))) * 8 + (k & 7);
    basep[off] = f2b(val);
}

// ---------------- per-node mean aggregation (32 lanes/node, uint4/lane, 8-deep MLP) ----------------
__global__ __launch_bounds__(256) void k_aggregate(const unsigned short* __restrict__ xb,
        const int* __restrict__ offs, const int* __restrict__ esrc,
        unsigned short* __restrict__ cb) {
    int gidx = blockIdx.x * 256 + threadIdx.x;
    int node = gidx >> 5;
    int lane = threadIdx.x & 31;
    if (node >= N_NODESC) return;
    int beg = offs[node], end = offs[node + 1];
    float a[8];
    #pragma unroll
    for (int j = 0; j < 8; j++) a[j] = 0.f;
    size_t loff = (size_t)lane * 8;
    int e = beg;
    for (; e + 8 <= end; e += 8) {
        int sidx[8];
        #pragma unroll
        for (int j = 0; j < 8; j++) sidx[j] = esrc[e + j];
        uint4 v[8];
        #pragma unroll
        for (int j = 0; j < 8; j++)
            v[j] = *(const uint4*)(xb + (size_t)sidx[j] * HIDC + loff);
        #pragma unroll
        for (int j = 0; j < 8; j++) {
            a[0] += blo(v[j].x); a[1] += bhi(v[j].x);
            a[2] += blo(v[j].y); a[3] += bhi(v[j].y);
            a[4] += blo(v[j].z); a[5] += bhi(v[j].z);
            a[6] += blo(v[j].w); a[7] += bhi(v[j].w);
        }
    }
    if (e + 4 <= end) {
        int sidx[4];
        #pragma unroll
        for (int j = 0; j < 4; j++) sidx[j] = esrc[e + j];
        uint4 v[4];
        #pragma unroll
        for (int j = 0; j < 4; j++)
            v[j] = *(const uint4*)(xb + (size_t)sidx[j] * HIDC + loff);
        #pragma unroll
        for (int j = 0; j < 4; j++) {
            a[0] += blo(v[j].x); a[1] += bhi(v[j].x);
            a[2] += blo(v[j].y); a[3] += bhi(v[j].y);
            a[4] += blo(v[j].z); a[5] += bhi(v[j].z);
            a[6] += blo(v[j].w); a[7] += bhi(v[j].w);
        }
        e += 4;
    }
    for (; e < end; e++) {
        uint4 v = *(const uint4*)(xb + (size_t)esrc[e] * HIDC + loff);
        a[0] += blo(v.x); a[1] += bhi(v.x);
        a[2] += blo(v.y); a[3] += bhi(v.y);
        a[4] += blo(v.z); a[5] += bhi(v.z);
        a[6] += blo(v.w); a[7] += bhi(v.w);
    }
    float w = 1.0f / (float)max(end - beg, 1);
    uint4 o;
    o.x = pkb(a[0] * w, a[1] * w);
    o.y = pkb(a[2] * w, a[3] * w);
    o.z = pkb(a[4] * w, a[5] * w);
    o.w = pkb(a[6] * w, a[7] * w);
    *(uint4*)(cb + (size_t)node * HIDC + loff) = o;
}

// ---------------- layer GEMM: 32-row blocks, direct row-major frag loads ----------------
// Block = 32 rows x 256 cols, 4 waves (wave wn -> cols wn*64..wn*64+63), K=512 (xb | cb).
// A-frag addr (row0+mt*16+l15)*512B + ks*64B + quad*16B: one wave instr = 16 full 64B lines.
// Epilogue: bias -> row L2-norm -> relu -> residual into xb.
__global__ __launch_bounds__(256) void k_lgemm(unsigned short* xb,
        const unsigned short* __restrict__ cbr, const unsigned short* __restrict__ wb,
        const float* __restrict__ bias) {
    __shared__ float rs[32];
    int tid = threadIdx.x;
    int wn = tid >> 6;
    int lane = tid & 63;
    int quad = lane >> 4;
    int l15 = lane & 15;
    int row0 = blockIdx.x * 32;

    floatx4 acc[2][4];
    #pragma unroll
    for (int mt = 0; mt < 2; mt++)
        #pragma unroll
        for (int n = 0; n < 4; n++)
            acc[mt][n] = (floatx4){0.f, 0.f, 0.f, 0.f};

    short8 aA[2], aB[2], bA[4], bB[4];
    auto loadA = [&](int ks, short8* a) {
        const unsigned short* base = (ks < 8) ? (const unsigned short*)xb : cbr;
        int ko = (ks & 7) * 32 + quad * 8;
        #pragma unroll
        for (int mt = 0; mt < 2; mt++)
            a[mt] = *(const short8*)(base + (size_t)(row0 + mt * 16 + l15) * HIDC + ko);
    };
    auto loadB = [&](int ks, short8* b) {
        const unsigned short* wp = wb + ((size_t)(ks * 16 + wn * 4) * 64 + lane) * 8;
        #pragma unroll
        for (int n = 0; n < 4; n++)
            b[n] = *(const short8*)(wp + n * 512);
    };
    auto step = [&](short8* a, short8* b) {
        #pragma unroll
        for (int mt = 0; mt < 2; mt++)
            #pragma unroll
            for (int n = 0; n < 4; n++)
                acc[mt][n] = __builtin_amdgcn_mfma_f32_16x16x32_bf16(a[mt], b[n], acc[mt][n], 0, 0, 0);
    };

    loadA(0, aA); loadB(0, bA);
    #pragma unroll
    for (int ks = 0; ks < 16; ks += 2) {
        loadA(ks + 1, aB); loadB(ks + 1, bB);
        step(aA, bA);
        if (ks + 2 < 16) { loadA(ks + 2, aA); loadB(ks + 2, bA); }
        step(aB, bB);
    }

    // bias
    float bv[4];
    #pragma unroll
    for (int n = 0; n < 4; n++) bv[n] = bias[wn * 64 + n * 16 + l15];
    #pragma unroll
    for (int mt = 0; mt < 2; mt++)
        #pragma unroll
        for (int n = 0; n < 4; n++)
            #pragma unroll
            for (int r = 0; r < 4; r++)
                acc[mt][n][r] += bv[n];

    // row sum-of-squares (16 cols in-wave via shfl, 4 col-waves via LDS)
    if (tid < 32) rs[tid] = 0.f;
    __syncthreads();
    #pragma unroll
    for (int mt = 0; mt < 2; mt++) {
        #pragma unroll
        for (int r = 0; r < 4; r++) {
            float p = acc[mt][0][r] * acc[mt][0][r] + acc[mt][1][r] * acc[mt][1][r]
                    + acc[mt][2][r] * acc[mt][2][r] + acc[mt][3][r] * acc[mt][3][r];
            p += __shfl_xor(p, 1);
            p += __shfl_xor(p, 2);
            p += __shfl_xor(p, 4);
            p += __shfl_xor(p, 8);
            if (l15 == 0) atomicAdd(&rs[mt * 16 + quad * 4 + r], p);
        }
    }
    __syncthreads();

    #pragma unroll
    for (int mt = 0; mt < 2; mt++) {
        #pragma unroll
        for (int r = 0; r < 4; r++) {
            int row = row0 + mt * 16 + quad * 4 + r;
            if (row < N_NODESC) {
                float inv = 1.0f / fmaxf(sqrtf(rs[mt * 16 + quad * 4 + r]), EPSV);
                #pragma unroll
                for (int n = 0; n < 4; n++) {
                    int col = wn * 64 + n * 16 + l15;
                    size_t idx = (size_t)row * HIDC + col;
                    float xo = b2f(xb[idx]);
                    float v = fmaxf(acc[mt][n][r] * inv, 0.f);
                    xb[idx] = f2b(xo + v);
                }
            }
        }
    }
}

// ---------------- embed GEMM: 32-row blocks, direct fp32 frag loads ----------------
__global__ __launch_bounds__(256) void k_egemm(const float* __restrict__ h,
        const unsigned short* __restrict__ wsw, const float* __restrict__ bias,
        unsigned short* __restrict__ xb) {
    int tid = threadIdx.x;
    int wn = tid >> 6;
    int lane = tid & 63;
    int quad = lane >> 4;
    int l15 = lane & 15;
    int row0 = blockIdx.x * 32;

    floatx4 acc[2][4];
    #pragma unroll
    for (int mt = 0; mt < 2; mt++)
        #pragma unroll
        for (int n = 0; n < 4; n++)
            acc[mt][n] = (floatx4){0.f, 0.f, 0.f, 0.f};

    short8 aA[2], aB[2], bA[4], bB[4];
    auto loadA = [&](int ks, short8* a) {
        #pragma unroll
        for (int mt = 0; mt < 2; mt++) {
            int row = row0 + mt * 16 + l15;
            float4 f0 = {0.f, 0.f, 0.f, 0.f}, f1 = {0.f, 0.f, 0.f, 0.f};
            if (row < N_NODESC) {
                const float* p = h + (size_t)row * IN_DIMC + ks * 32 + quad * 8;
                f0 = *(const float4*)p;
                f1 = *(const float4*)(p + 4);
            }
            uint4 av;
            av.x = pkb(f0.x, f0.y); av.y = pkb(f0.z, f0.w);
            av.z = pkb(f1.x, f1.y); av.w = pkb(f1.z, f1.w);
            a[mt] = *(short8*)&av;
        }
    };
    auto loadB = [&](int ks, short8* b) {
        const unsigned short* wp = wsw + ((size_t)(ks * 16 + wn * 4) * 64 + lane) * 8;
        #pragma unroll
        for (int n = 0; n < 4; n++)
            b[n] = *(const short8*)(wp + n * 512);
    };
    auto step = [&](short8* a, short8* b) {
        #pragma unroll
        for (int mt = 0; mt < 2; mt++)
            #pragma unroll
            for (int n = 0; n < 4; n++)
                acc[mt][n] = __builtin_amdgcn_mfma_f32_16x16x32_bf16(a[mt], b[n], acc[mt][n], 0, 0, 0);
    };

    loadA(0, aA); loadB(0, bA);
    #pragma unroll
    for (int ks = 0; ks < 4; ks += 2) {
        loadA(ks + 1, aB); loadB(ks + 1, bB);
        step(aA, bA);
        if (ks + 2 < 4) { loadA(ks + 2, aA); loadB(ks + 2, bA); }
        step(aB, bB);
    }

    float bv[4];
    #pragma unroll
    for (int n = 0; n < 4; n++) bv[n] = bias[wn * 64 + n * 16 + l15];
    #pragma unroll
    for (int mt = 0; mt < 2; mt++) {
        #pragma unroll
        for (int r = 0; r < 4; r++) {
            int row = row0 + mt * 16 + quad * 4 + r;
            if (row < N_NODESC) {
                #pragma unroll
                for (int n = 0; n < 4; n++) {
                    int col = wn * 64 + n * 16 + l15;
                    xb[(size_t)row * HIDC + col] = f2b(acc[mt][n][r] + bv[n]);
                }
            }
        }
    }
}

// ---------------- graph mean-pool: 1 block per (graph, 64-col quarter) ----------------
__global__ __launch_bounds__(256) void k_pool(const unsigned short* __restrict__ xb,
        const int* __restrict__ gstart, float* __restrict__ hg) {
    __shared__ float red[256][8];
    int g = blockIdx.x >> 2;
    int cq = blockIdx.x & 3;
    int t = threadIdx.x;
    int cchunk = t & 7;
    int rgrp = t >> 3;
    int col0 = cq * 64 + cchunk * 8;
    int beg = gstart[g], end = gstart[g + 1];
    float a[8];
    #pragma unroll
    for (int j = 0; j < 8; j++) a[j] = 0.f;
    for (int r = beg + rgrp; r < end; r += 32) {
        uint4 v = *(const uint4*)(xb + (size_t)r * HIDC + col0);
        a[0] += blo(v.x); a[1] += bhi(v.x);
        a[2] += blo(v.y); a[3] += bhi(v.y);
        a[4] += blo(v.z); a[5] += bhi(v.z);
        a[6] += blo(v.w); a[7] += bhi(v.w);
    }
    #pragma unroll
    for (int j = 0; j < 8; j++) red[t][j] = a[j];
    __syncthreads();
    for (int d = 16; d >= 1; d >>= 1) {
        if (rgrp < d) {
            #pragma unroll
            for (int j = 0; j < 8; j++) red[t][j] += red[t + d * 8][j];
        }
        __syncthreads();
    }
    if (rgrp == 0) {
        float inv = 1.0f / (float)max(end - beg, 1);
        #pragma unroll
        for (int j = 0; j < 8; j++)
            hg[g * HIDC + col0 + j] = red[t][j] * inv;
    }
}

// ---------------- readout ----------------
__global__ __launch_bounds__(256) void k_readout(const float* __restrict__ hg,
        const float* __restrict__ ppos, const float* __restrict__ pneg,
        const float* __restrict__ wfc, float* __restrict__ out) {
    __shared__ float red[256];
    __shared__ float ss[10];
    int t = threadIdx.x;
    int g = blockIdx.x;
    float hgv = hg[g * HIDC + t];
    for (int p = 0; p < 10; p++) {
        const float* P = (p < 5) ? (ppos + p * HIDC) : (pneg + (p - 5) * HIDC);
        float d = hgv - P[t];
        red[t] = d * d;
        __syncthreads();
        for (int s2 = 128; s2 > 0; s2 >>= 1) {
            if (t < s2) red[t] += red[t + s2];
            __syncthreads();
        }
        if (t == 0) {
            float dd = red[0];
            ss[p] = logf((dd + 1.0f) / (dd + EPSV));
        }
        __syncthreads();
    }
    if (t == 0) {
        float y = 0.f;
        #pragma unroll
        for (int p = 0; p < 10; p++) y += ss[p] * wfc[p];
        out[g] = 1.0f / (1.0f + expf(-y));
    }
}

extern "C" void kernel_launch(void* const* d_in, const int* in_sizes, int n_in,
                              void* d_out, int out_size, void* d_ws, size_t ws_size,
                              hipStream_t stream) {
    const float* h    = (const float*)d_in[0];
    const int*   src  = (const int*)d_in[1];
    const int*   dst  = (const int*)d_in[2];
    const int*   gid  = (const int*)d_in[3];
    const float* Wemb = (const float*)d_in[4];
    const float* bemb = (const float*)d_in[5];
    const float* Ws   = (const float*)d_in[6];
    const float* bs   = (const float*)d_in[7];
    const float* ppos = (const float*)d_in[8];
    const float* pneg = (const float*)d_in[9];
    const float* wfc  = (const float*)d_in[10];
    float* out = (float*)d_out;

    char* ws = (char*)d_ws;
    size_t off = 0;
    auto alloc = [&](size_t bytes) {
        void* p = ws + off;
        off += (bytes + 255) & ~(size_t)255;
        return p;
    };
    unsigned short* xb  = (unsigned short*)alloc((size_t)NPAD * HIDC * 2);  // row-major
    unsigned short* cb  = (unsigned short*)alloc((size_t)NPAD * HIDC * 2);  // row-major
    unsigned short* wsw = (unsigned short*)alloc((size_t)(IN_DIMC * HIDC + N_LAYERSC * 2 * HIDC * HIDC) * 2);
    int*   deg    = (int*)alloc((size_t)N_NODESC * 4);
    int*   offs   = (int*)alloc((size_t)(N_NODESC + 1) * 4);
    int*   cursor = (int*)alloc((size_t)N_NODESC * 4);
    int*   esrc   = (int*)alloc((size_t)N_EDGESC * 4);
    int*   bsum   = (int*)alloc((size_t)SCAN_BLK * 4);
    int*   boff   = (int*)alloc((size_t)SCAN_BLK * 4);
    int*   gstart = (int*)alloc((size_t)(N_GRAPHSC + 1) * 4);
    float* hg     = (float*)alloc((size_t)N_GRAPHSC * HIDC * 4);
    (void)ws_size; (void)in_sizes; (void)n_in; (void)out_size;

    hipMemsetAsync(deg, 0, (size_t)N_NODESC * 4, stream);

    const int WTOT = IN_DIMC * HIDC + N_LAYERSC * 2 * HIDC * HIDC; // 557056
    k_wconv<<<(WTOT + 255) / 256, 256, 0, stream>>>(Wemb, Ws, wsw);
    k_count<<<(N_EDGESC + 255) / 256, 256, 0, stream>>>(dst, deg);
    k_gbounds<<<1, 128, 0, stream>>>(gid, gstart);
    k_scanA<<<SCAN_BLK, 256, 0, stream>>>(deg, bsum);
    k_scanB<<<1, 256, 0, stream>>>(bsum, boff);
    k_scanC<<<SCAN_BLK, 256, 0, stream>>>(deg, boff, offs, cursor);
    k_scatter<<<(N_EDGESC + 255) / 256, 256, 0, stream>>>(src, dst, cursor, esrc);

    const int GBLK = NPAD / 32; // 1564
    k_egemm<<<GBLK, 256, 0, stream>>>(h, wsw, bemb, xb);

    for (int l = 0; l < N_LAYERSC; l++) {
        k_aggregate<<<(N_NODESC * 32 + 255) / 256, 256, 0, stream>>>(xb, offs, esrc, cb);
        k_lgemm<<<GBLK, 256, 0, stream>>>(
            xb, cb,
            wsw + IN_DIMC * HIDC + (size_t)l * 2 * HIDC * HIDC,
            bs + (size_t)l * HIDC);
    }
    k_pool<<<N_GRAPHSC * 4, 256, 0, stream>>>(xb, gstart, hg);
    k_readout<<<N_GRAPHSC, 256, 0, stream>>>(hg, ppos, pneg, wfc, out);
}

// Round 8
// 566.329 us; speedup vs baseline: 1.2309x; 1.1377x over previous
//
#include <hip/hip_runtime.h>
#include <math.h>

#define N_NODESC 50000
#define NPAD 50048              // 1564 * 32
#define N_EDGESC 800000
#define N_GRAPHSC 64
#define IN_DIMC 128
#define HIDC 256
#define N_LAYERSC 4
#define EPSV 1e-12f

#define SCAN_BLK 196  // ceil(50000/256)

typedef __attribute__((ext_vector_type(8))) short short8;
typedef __attribute__((ext_vector_type(4))) float floatx4;
typedef __attribute__((ext_vector_type(2))) float floatx2;

__device__ __forceinline__ unsigned short f2b(float f) {
    union { float f; unsigned u; } v; v.f = f;
    unsigned r = v.u + 0x7FFFu + ((v.u >> 16) & 1u);
    return (unsigned short)(r >> 16);
}
__device__ __forceinline__ float blo(unsigned u) { return __uint_as_float(u << 16); }
__device__ __forceinline__ float bhi(unsigned u) { return __uint_as_float(u & 0xFFFF0000u); }
__device__ __forceinline__ unsigned pkb(float a, float b) {
    return (unsigned)f2b(a) | ((unsigned)f2b(b) << 16);
}
__device__ __forceinline__ float b2f(unsigned short s) {
    return __uint_as_float((unsigned)s << 16);
}
__device__ __forceinline__ unsigned char f2q(float v) {
    return (unsigned char)(__builtin_amdgcn_cvt_pk_fp8_f32(v, v, 0, false) & 0xFF);
}

// ---------------- degree count ----------------
__global__ void k_count(const int* __restrict__ dst, int* __restrict__ deg) {
    int e = blockIdx.x * blockDim.x + threadIdx.x;
    if (e < N_EDGESC) atomicAdd(&deg[dst[e]], 1);
}

// ---------------- graph boundaries via binary search (gid sorted) ----------------
__global__ __launch_bounds__(128) void k_gbounds(const int* __restrict__ gid,
        int* __restrict__ gstart) {
    int g = threadIdx.x;
    if (g > N_GRAPHSC) return;
    int lo = 0, hi = N_NODESC;
    while (lo < hi) {
        int mid = (lo + hi) >> 1;
        if (gid[mid] < g) lo = mid + 1; else hi = mid;
    }
    gstart[g] = lo;
}

// ---------------- hierarchical scan ----------------
__global__ __launch_bounds__(256) void k_scanA(const int* __restrict__ deg,
        int* __restrict__ bsum) {
    __shared__ int s[256];
    int t = threadIdx.x;
    int i = blockIdx.x * 256 + t;
    s[t] = (i < N_NODESC) ? deg[i] : 0;
    __syncthreads();
    for (int d = 128; d > 0; d >>= 1) {
        if (t < d) s[t] += s[t + d];
        __syncthreads();
    }
    if (t == 0) bsum[blockIdx.x] = s[0];
}

__global__ __launch_bounds__(256) void k_scanB(const int* __restrict__ bsum,
        int* __restrict__ boff) {
    __shared__ int s[256];
    int t = threadIdx.x;
    int v = (t < SCAN_BLK) ? bsum[t] : 0;
    s[t] = v;
    __syncthreads();
    for (int d = 1; d < 256; d <<= 1) {
        int u = (t >= d) ? s[t - d] : 0;
        __syncthreads();
        s[t] += u;
        __syncthreads();
    }
    if (t < SCAN_BLK) boff[t] = s[t] - v;
}

__global__ __launch_bounds__(256) void k_scanC(const int* __restrict__ deg,
        const int* __restrict__ boff, int* __restrict__ offs, int* __restrict__ cursor) {
    __shared__ int s[256];
    int t = threadIdx.x;
    int i = blockIdx.x * 256 + t;
    int v = (i < N_NODESC) ? deg[i] : 0;
    s[t] = v;
    __syncthreads();
    for (int d = 1; d < 256; d <<= 1) {
        int u = (t >= d) ? s[t - d] : 0;
        __syncthreads();
        s[t] += u;
        __syncthreads();
    }
    int excl = s[t] - v + boff[blockIdx.x];
    if (i < N_NODESC) {
        offs[i] = excl;
        cursor[i] = excl;
        if (i == N_NODESC - 1) offs[N_NODESC] = excl + v;
    }
}

// ---------------- scatter edges into CSR buckets ----------------
__global__ void k_scatter(const int* __restrict__ src, const int* __restrict__ dst,
        int* __restrict__ cursor, int* __restrict__ esrc) {
    int e = blockIdx.x * blockDim.x + threadIdx.x;
    if (e < N_EDGESC) {
        int d = dst[e];
        int pos = atomicAdd(&cursor[d], 1);
        esrc[pos] = src[e];
    }
}

// ---------------- weight convert + swizzle to MFMA B-fragment order ----------------
__global__ __launch_bounds__(256) void k_wconv(const float* __restrict__ Wemb,
        const float* __restrict__ Ws, unsigned short* __restrict__ wsw) {
    int idx = blockIdx.x * 256 + threadIdx.x;
    const int EMB = IN_DIMC * HIDC;           // 32768
    const int LYR = 2 * HIDC * HIDC;          // 131072
    if (idx >= EMB + N_LAYERSC * LYR) return;
    float val; int k, n; unsigned short* basep;
    if (idx < EMB) {
        k = idx >> 8; n = idx & 255;
        val = Wemb[idx];
        basep = wsw;
    } else {
        int r = idx - EMB;
        int l = r >> 17;
        int r2 = r & (LYR - 1);
        k = r2 >> 8; n = r2 & 255;
        val = Ws[r];
        basep = wsw + EMB + l * LYR;
    }
    int off = (((k >> 5) * 16 + (n >> 4)) * 64 + ((((k >> 3) & 3) << 4) | (n & 15))) * 8 + (k & 7);
    basep[off] = f2b(val);
}

// ---------------- per-node mean aggregation: fp8 gather, fp32 acc, bf16 out ----------------
__global__ __launch_bounds__(256) void k_aggregate(const unsigned char* __restrict__ xq,
        const int* __restrict__ offs, const int* __restrict__ esrc,
        unsigned short* __restrict__ cb) {
    int gidx = blockIdx.x * 256 + threadIdx.x;
    int node = gidx >> 5;
    int lane = threadIdx.x & 31;
    if (node >= N_NODESC) return;
    int beg = offs[node], end = offs[node + 1];
    float a[8];
    #pragma unroll
    for (int j = 0; j < 8; j++) a[j] = 0.f;
    size_t loff = (size_t)lane * 8;
    int e = beg;
    #define ACC8(v) do { \
        floatx2 t0 = __builtin_amdgcn_cvt_pk_f32_fp8((v).x, false); \
        floatx2 t1 = __builtin_amdgcn_cvt_pk_f32_fp8((v).x, true);  \
        floatx2 t2 = __builtin_amdgcn_cvt_pk_f32_fp8((v).y, false); \
        floatx2 t3 = __builtin_amdgcn_cvt_pk_f32_fp8((v).y, true);  \
        a[0] += t0.x; a[1] += t0.y; a[2] += t1.x; a[3] += t1.y;     \
        a[4] += t2.x; a[5] += t2.y; a[6] += t3.x; a[7] += t3.y;     \
    } while (0)
    for (; e + 8 <= end; e += 8) {
        int sidx[8];
        #pragma unroll
        for (int j = 0; j < 8; j++) sidx[j] = esrc[e + j];
        uint2 v[8];
        #pragma unroll
        for (int j = 0; j < 8; j++)
            v[j] = *(const uint2*)(xq + (size_t)sidx[j] * HIDC + loff);
        #pragma unroll
        for (int j = 0; j < 8; j++) ACC8(v[j]);
    }
    if (e + 4 <= end) {
        int sidx[4];
        #pragma unroll
        for (int j = 0; j < 4; j++) sidx[j] = esrc[e + j];
        uint2 v[4];
        #pragma unroll
        for (int j = 0; j < 4; j++)
            v[j] = *(const uint2*)(xq + (size_t)sidx[j] * HIDC + loff);
        #pragma unroll
        for (int j = 0; j < 4; j++) ACC8(v[j]);
        e += 4;
    }
    for (; e < end; e++) {
        uint2 v = *(const uint2*)(xq + (size_t)esrc[e] * HIDC + loff);
        ACC8(v);
    }
    #undef ACC8
    float w = 1.0f / (float)max(end - beg, 1);
    uint4 o;
    o.x = pkb(a[0] * w, a[1] * w);
    o.y = pkb(a[2] * w, a[3] * w);
    o.z = pkb(a[4] * w, a[5] * w);
    o.w = pkb(a[6] * w, a[7] * w);
    *(uint4*)(cb + (size_t)node * HIDC + loff) = o;
}

// ---------------- layer GEMM: 32-row blocks, direct row-major frag loads ----------------
__global__ __launch_bounds__(256) void k_lgemm(unsigned short* xb,
        const unsigned short* __restrict__ cbr, const unsigned short* __restrict__ wb,
        const float* __restrict__ bias, unsigned char* __restrict__ xq) {
    __shared__ float rs[32];
    int tid = threadIdx.x;
    int wn = tid >> 6;
    int lane = tid & 63;
    int quad = lane >> 4;
    int l15 = lane & 15;
    int row0 = blockIdx.x * 32;

    floatx4 acc[2][4];
    #pragma unroll
    for (int mt = 0; mt < 2; mt++)
        #pragma unroll
        for (int n = 0; n < 4; n++)
            acc[mt][n] = (floatx4){0.f, 0.f, 0.f, 0.f};

    short8 aA[2], aB[2], bA[4], bB[4];
    auto loadA = [&](int ks, short8* a) {
        const unsigned short* base = (ks < 8) ? (const unsigned short*)xb : cbr;
        int ko = (ks & 7) * 32 + quad * 8;
        #pragma unroll
        for (int mt = 0; mt < 2; mt++)
            a[mt] = *(const short8*)(base + (size_t)(row0 + mt * 16 + l15) * HIDC + ko);
    };
    auto loadB = [&](int ks, short8* b) {
        const unsigned short* wp = wb + ((size_t)(ks * 16 + wn * 4) * 64 + lane) * 8;
        #pragma unroll
        for (int n = 0; n < 4; n++)
            b[n] = *(const short8*)(wp + n * 512);
    };
    auto step = [&](short8* a, short8* b) {
        #pragma unroll
        for (int mt = 0; mt < 2; mt++)
            #pragma unroll
            for (int n = 0; n < 4; n++)
                acc[mt][n] = __builtin_amdgcn_mfma_f32_16x16x32_bf16(a[mt], b[n], acc[mt][n], 0, 0, 0);
    };

    loadA(0, aA); loadB(0, bA);
    #pragma unroll
    for (int ks = 0; ks < 16; ks += 2) {
        loadA(ks + 1, aB); loadB(ks + 1, bB);
        step(aA, bA);
        if (ks + 2 < 16) { loadA(ks + 2, aA); loadB(ks + 2, bA); }
        step(aB, bB);
    }

    float bv[4];
    #pragma unroll
    for (int n = 0; n < 4; n++) bv[n] = bias[wn * 64 + n * 16 + l15];
    #pragma unroll
    for (int mt = 0; mt < 2; mt++)
        #pragma unroll
        for (int n = 0; n < 4; n++)
            #pragma unroll
            for (int r = 0; r < 4; r++)
                acc[mt][n][r] += bv[n];

    if (tid < 32) rs[tid] = 0.f;
    __syncthreads();
    #pragma unroll
    for (int mt = 0; mt < 2; mt++) {
        #pragma unroll
        for (int r = 0; r < 4; r++) {
            float p = acc[mt][0][r] * acc[mt][0][r] + acc[mt][1][r] * acc[mt][1][r]
                    + acc[mt][2][r] * acc[mt][2][r] + acc[mt][3][r] * acc[mt][3][r];
            p += __shfl_xor(p, 1);
            p += __shfl_xor(p, 2);
            p += __shfl_xor(p, 4);
            p += __shfl_xor(p, 8);
            if (l15 == 0) atomicAdd(&rs[mt * 16 + quad * 4 + r], p);
        }
    }
    __syncthreads();

    #pragma unroll
    for (int mt = 0; mt < 2; mt++) {
        #pragma unroll
        for (int r = 0; r < 4; r++) {
            int row = row0 + mt * 16 + quad * 4 + r;
            if (row < N_NODESC) {
                float inv = 1.0f / fmaxf(sqrtf(rs[mt * 16 + quad * 4 + r]), EPSV);
                #pragma unroll
                for (int n = 0; n < 4; n++) {
                    int col = wn * 64 + n * 16 + l15;
                    size_t idx = (size_t)row * HIDC + col;
                    float xo = b2f(xb[idx]);
                    float v = fmaxf(acc[mt][n][r] * inv, 0.f);
                    float nv = xo + v;
                    xb[idx] = f2b(nv);
                    xq[idx] = f2q(nv);
                }
            }
        }
    }
}

// ---------------- embed GEMM: 32-row blocks, direct fp32 frag loads ----------------
__global__ __launch_bounds__(256) void k_egemm(const float* __restrict__ h,
        const unsigned short* __restrict__ wsw, const float* __restrict__ bias,
        unsigned short* __restrict__ xb, unsigned char* __restrict__ xq) {
    int tid = threadIdx.x;
    int wn = tid >> 6;
    int lane = tid & 63;
    int quad = lane >> 4;
    int l15 = lane & 15;
    int row0 = blockIdx.x * 32;

    floatx4 acc[2][4];
    #pragma unroll
    for (int mt = 0; mt < 2; mt++)
        #pragma unroll
        for (int n = 0; n < 4; n++)
            acc[mt][n] = (floatx4){0.f, 0.f, 0.f, 0.f};

    short8 aA[2], aB[2], bA[4], bB[4];
    auto loadA = [&](int ks, short8* a) {
        #pragma unroll
        for (int mt = 0; mt < 2; mt++) {
            int row = row0 + mt * 16 + l15;
            float4 f0 = {0.f, 0.f, 0.f, 0.f}, f1 = {0.f, 0.f, 0.f, 0.f};
            if (row < N_NODESC) {
                const float* p = h + (size_t)row * IN_DIMC + ks * 32 + quad * 8;
                f0 = *(const float4*)p;
                f1 = *(const float4*)(p + 4);
            }
            uint4 av;
            av.x = pkb(f0.x, f0.y); av.y = pkb(f0.z, f0.w);
            av.z = pkb(f1.x, f1.y); av.w = pkb(f1.z, f1.w);
            a[mt] = *(short8*)&av;
        }
    };
    auto loadB = [&](int ks, short8* b) {
        const unsigned short* wp = wsw + ((size_t)(ks * 16 + wn * 4) * 64 + lane) * 8;
        #pragma unroll
        for (int n = 0; n < 4; n++)
            b[n] = *(const short8*)(wp + n * 512);
    };
    auto step = [&](short8* a, short8* b) {
        #pragma unroll
        for (int mt = 0; mt < 2; mt++)
            #pragma unroll
            for (int n = 0; n < 4; n++)
                acc[mt][n] = __builtin_amdgcn_mfma_f32_16x16x32_bf16(a[mt], b[n], acc[mt][n], 0, 0, 0);
    };

    loadA(0, aA); loadB(0, bA);
    #pragma unroll
    for (int ks = 0; ks < 4; ks += 2) {
        loadA(ks + 1, aB); loadB(ks + 1, bB);
        step(aA, bA);
        if (ks + 2 < 4) { loadA(ks + 2, aA); loadB(ks + 2, bA); }
        step(aB, bB);
    }

    float bv[4];
    #pragma unroll
    for (int n = 0; n < 4; n++) bv[n] = bias[wn * 64 + n * 16 + l15];
    #pragma unroll
    for (int mt = 0; mt < 2; mt++) {
        #pragma unroll
        for (int r = 0; r < 4; r++) {
            int row = row0 + mt * 16 + quad * 4 + r;
            if (row < N_NODESC) {
                #pragma unroll
                for (int n = 0; n < 4; n++) {
                    int col = wn * 64 + n * 16 + l15;
                    float v = acc[mt][n][r] + bv[n];
                    size_t idx = (size_t)row * HIDC + col;
                    xb[idx] = f2b(v);
                    xq[idx] = f2q(v);
                }
            }
        }
    }
}

// ---------------- graph mean-pool: 1 block per (graph, 64-col quarter) ----------------
__global__ __launch_bounds__(256) void k_pool(const unsigned short* __restrict__ xb,
        const int* __restrict__ gstart, float* __restrict__ hg) {
    __shared__ float red[256][8];
    int g = blockIdx.x >> 2;
    int cq = blockIdx.x & 3;
    int t = threadIdx.x;
    int cchunk = t & 7;
    int rgrp = t >> 3;
    int col0 = cq * 64 + cchunk * 8;
    int beg = gstart[g], end = gstart[g + 1];
    float a[8];
    #pragma unroll
    for (int j = 0; j < 8; j++) a[j] = 0.f;
    for (int r = beg + rgrp; r < end; r += 32) {
        uint4 v = *(const uint4*)(xb + (size_t)r * HIDC + col0);
        a[0] += blo(v.x); a[1] += bhi(v.x);
        a[2] += blo(v.y); a[3] += bhi(v.y);
        a[4] += blo(v.z); a[5] += bhi(v.z);
        a[6] += blo(v.w); a[7] += bhi(v.w);
    }
    #pragma unroll
    for (int j = 0; j < 8; j++) red[t][j] = a[j];
    __syncthreads();
    for (int d = 16; d >= 1; d >>= 1) {
        if (rgrp < d) {
            #pragma unroll
            for (int j = 0; j < 8; j++) red[t][j] += red[t + d * 8][j];
        }
        __syncthreads();
    }
    if (rgrp == 0) {
        float inv = 1.0f / (float)max(end - beg, 1);
        #pragma unroll
        for (int j = 0; j < 8; j++)
            hg[g * HIDC + col0 + j] = red[t][j] * inv;
    }
}

// ---------------- readout ----------------
__global__ __launch_bounds__(256) void k_readout(const float* __restrict__ hg,
        const float* __restrict__ ppos, const float* __restrict__ pneg,
        const float* __restrict__ wfc, float* __restrict__ out) {
    __shared__ float red[256];
    __shared__ float ss[10];
    int t = threadIdx.x;
    int g = blockIdx.x;
    float hgv = hg[g * HIDC + t];
    for (int p = 0; p < 10; p++) {
        const float* P = (p < 5) ? (ppos + p * HIDC) : (pneg + (p - 5) * HIDC);
        float d = hgv - P[t];
        red[t] = d * d;
        __syncthreads();
        for (int s2 = 128; s2 > 0; s2 >>= 1) {
            if (t < s2) red[t] += red[t + s2];
            __syncthreads();
        }
        if (t == 0) {
            float dd = red[0];
            ss[p] = logf((dd + 1.0f) / (dd + EPSV));
        }
        __syncthreads();
    }
    if (t == 0) {
        float y = 0.f;
        #pragma unroll
        for (int p = 0; p < 10; p++) y += ss[p] * wfc[p];
        out[g] = 1.0f / (1.0f + expf(-y));
    }
}

extern "C" void kernel_launch(void* const* d_in, const int* in_sizes, int n_in,
                              void* d_out, int out_size, void* d_ws, size_t ws_size,
                              hipStream_t stream) {
    const float* h    = (const float*)d_in[0];
    const int*   src  = (const int*)d_in[1];
    const int*   dst  = (const int*)d_in[2];
    const int*   gid  = (const int*)d_in[3];
    const float* Wemb = (const float*)d_in[4];
    const float* bemb = (const float*)d_in[5];
    const float* Ws   = (const float*)d_in[6];
    const float* bs   = (const float*)d_in[7];
    const float* ppos = (const float*)d_in[8];
    const float* pneg = (const float*)d_in[9];
    const float* wfc  = (const float*)d_in[10];
    float* out = (float*)d_out;

    char* ws = (char*)d_ws;
    size_t off = 0;
    auto alloc = [&](size_t bytes) {
        void* p = ws + off;
        off += (bytes + 255) & ~(size_t)255;
        return p;
    };
    unsigned short* xb  = (unsigned short*)alloc((size_t)NPAD * HIDC * 2);  // bf16 row-major
    unsigned char*  xq  = (unsigned char*)alloc((size_t)NPAD * HIDC);       // fp8 shadow
    unsigned short* cb  = (unsigned short*)alloc((size_t)NPAD * HIDC * 2);  // bf16 row-major
    unsigned short* wsw = (unsigned short*)alloc((size_t)(IN_DIMC * HIDC + N_LAYERSC * 2 * HIDC * HIDC) * 2);
    int*   deg    = (int*)alloc((size_t)N_NODESC * 4);
    int*   offs   = (int*)alloc((size_t)(N_NODESC + 1) * 4);
    int*   cursor = (int*)alloc((size_t)N_NODESC * 4);
    int*   esrc   = (int*)alloc((size_t)N_EDGESC * 4);
    int*   bsum   = (int*)alloc((size_t)SCAN_BLK * 4);
    int*   boff   = (int*)alloc((size_t)SCAN_BLK * 4);
    int*   gstart = (int*)alloc((size_t)(N_GRAPHSC + 1) * 4);
    float* hg     = (float*)alloc((size_t)N_GRAPHSC * HIDC * 4);
    (void)ws_size; (void)in_sizes; (void)n_in; (void)out_size;

    hipMemsetAsync(deg, 0, (size_t)N_NODESC * 4, stream);

    const int WTOT = IN_DIMC * HIDC + N_LAYERSC * 2 * HIDC * HIDC; // 557056
    k_wconv<<<(WTOT + 255) / 256, 256, 0, stream>>>(Wemb, Ws, wsw);
    k_count<<<(N_EDGESC + 255) / 256, 256, 0, stream>>>(dst, deg);
    k_gbounds<<<1, 128, 0, stream>>>(gid, gstart);
    k_scanA<<<SCAN_BLK, 256, 0, stream>>>(deg, bsum);
    k_scanB<<<1, 256, 0, stream>>>(bsum, boff);
    k_scanC<<<SCAN_BLK, 256, 0, stream>>>(deg, boff, offs, cursor);
    k_scatter<<<(N_EDGESC + 255) / 256, 256, 0, stream>>>(src, dst, cursor, esrc);

    const int GBLK = NPAD / 32; // 1564
    k_egemm<<<GBLK, 256, 0, stream>>>(h, wsw, bemb, xb, xq);

    for (int l = 0; l < N_LAYERSC; l++) {
        k_aggregate<<<(N_NODESC * 32 + 255) / 256, 256, 0, stream>>>(xq, offs, esrc, cb);
        k_lgemm<<<GBLK, 256, 0, stream>>>(
            xb, cb,
            wsw + IN_DIMC * HIDC + (size_t)l * 2 * HIDC * HIDC,
            bs + (size_t)l * HIDC, xq);
    }
    k_pool<<<N_GRAPHSC * 4, 256, 0, stream>>>(xb, gstart, hg);
    k_readout<<<N_GRAPHSC, 256, 0, stream>>>(hg, ppos, pneg, wfc, out);
}

// Round 9
// 563.724 us; speedup vs baseline: 1.2365x; 1.0046x over previous
//
#include <hip/hip_runtime.h>
#include <math.h>

#define N_NODESC 50000
#define NPAD 50048              // 1564 * 32
#define N_EDGESC 800000
#define N_GRAPHSC 64
#define IN_DIMC 128
#define HIDC 256
#define N_LAYERSC 4
#define EPSV 1e-12f

#define SCAN_BLK 196  // ceil(50000/256)

typedef __attribute__((ext_vector_type(8))) short short8;
typedef __attribute__((ext_vector_type(4))) float floatx4;
typedef __attribute__((ext_vector_type(2))) float floatx2;

__device__ __forceinline__ unsigned short f2b(float f) {
    union { float f; unsigned u; } v; v.f = f;
    unsigned r = v.u + 0x7FFFu + ((v.u >> 16) & 1u);
    return (unsigned short)(r >> 16);
}
__device__ __forceinline__ float blo(unsigned u) { return __uint_as_float(u << 16); }
__device__ __forceinline__ float bhi(unsigned u) { return __uint_as_float(u & 0xFFFF0000u); }
__device__ __forceinline__ unsigned pkb(float a, float b) {
    return (unsigned)f2b(a) | ((unsigned)f2b(b) << 16);
}
__device__ __forceinline__ float b2f(unsigned short s) {
    return __uint_as_float((unsigned)s << 16);
}
__device__ __forceinline__ unsigned char f2q(float v) {
    return (unsigned char)(__builtin_amdgcn_cvt_pk_fp8_f32(v, v, 0, false) & 0xFF);
}

// ---------------- degree count ----------------
__global__ void k_count(const int* __restrict__ dst, int* __restrict__ deg) {
    int e = blockIdx.x * blockDim.x + threadIdx.x;
    if (e < N_EDGESC) atomicAdd(&deg[dst[e]], 1);
}

// ---------------- graph boundaries via binary search (gid sorted) ----------------
__global__ __launch_bounds__(128) void k_gbounds(const int* __restrict__ gid,
        int* __restrict__ gstart) {
    int g = threadIdx.x;
    if (g > N_GRAPHSC) return;
    int lo = 0, hi = N_NODESC;
    while (lo < hi) {
        int mid = (lo + hi) >> 1;
        if (gid[mid] < g) lo = mid + 1; else hi = mid;
    }
    gstart[g] = lo;
}

// ---------------- hierarchical scan ----------------
__global__ __launch_bounds__(256) void k_scanA(const int* __restrict__ deg,
        int* __restrict__ bsum) {
    __shared__ int s[256];
    int t = threadIdx.x;
    int i = blockIdx.x * 256 + t;
    s[t] = (i < N_NODESC) ? deg[i] : 0;
    __syncthreads();
    for (int d = 128; d > 0; d >>= 1) {
        if (t < d) s[t] += s[t + d];
        __syncthreads();
    }
    if (t == 0) bsum[blockIdx.x] = s[0];
}

__global__ __launch_bounds__(256) void k_scanB(const int* __restrict__ bsum,
        int* __restrict__ boff) {
    __shared__ int s[256];
    int t = threadIdx.x;
    int v = (t < SCAN_BLK) ? bsum[t] : 0;
    s[t] = v;
    __syncthreads();
    for (int d = 1; d < 256; d <<= 1) {
        int u = (t >= d) ? s[t - d] : 0;
        __syncthreads();
        s[t] += u;
        __syncthreads();
    }
    if (t < SCAN_BLK) boff[t] = s[t] - v;
}

__global__ __launch_bounds__(256) void k_scanC(const int* __restrict__ deg,
        const int* __restrict__ boff, int* __restrict__ offs, int* __restrict__ cursor) {
    __shared__ int s[256];
    int t = threadIdx.x;
    int i = blockIdx.x * 256 + t;
    int v = (i < N_NODESC) ? deg[i] : 0;
    s[t] = v;
    __syncthreads();
    for (int d = 1; d < 256; d <<= 1) {
        int u = (t >= d) ? s[t - d] : 0;
        __syncthreads();
        s[t] += u;
        __syncthreads();
    }
    int excl = s[t] - v + boff[blockIdx.x];
    if (i < N_NODESC) {
        offs[i] = excl;
        cursor[i] = excl;
        if (i == N_NODESC - 1) offs[N_NODESC] = excl + v;
    }
}

// ---------------- scatter edges into CSR buckets ----------------
__global__ void k_scatter(const int* __restrict__ src, const int* __restrict__ dst,
        int* __restrict__ cursor, int* __restrict__ esrc) {
    int e = blockIdx.x * blockDim.x + threadIdx.x;
    if (e < N_EDGESC) {
        int d = dst[e];
        int pos = atomicAdd(&cursor[d], 1);
        esrc[pos] = src[e];
    }
}

// ---------------- weight convert + swizzle to MFMA B-fragment order ----------------
__global__ __launch_bounds__(256) void k_wconv(const float* __restrict__ Wemb,
        const float* __restrict__ Ws, unsigned short* __restrict__ wsw) {
    int idx = blockIdx.x * 256 + threadIdx.x;
    const int EMB = IN_DIMC * HIDC;           // 32768
    const int LYR = 2 * HIDC * HIDC;          // 131072
    if (idx >= EMB + N_LAYERSC * LYR) return;
    float val; int k, n; unsigned short* basep;
    if (idx < EMB) {
        k = idx >> 8; n = idx & 255;
        val = Wemb[idx];
        basep = wsw;
    } else {
        int r = idx - EMB;
        int l = r >> 17;
        int r2 = r & (LYR - 1);
        k = r2 >> 8; n = r2 & 255;
        val = Ws[r];
        basep = wsw + EMB + l * LYR;
    }
    int off = (((k >> 5) * 16 + (n >> 4)) * 64 + ((((k >> 3) & 3) << 4) | (n & 15))) * 8 + (k & 7);
    basep[off] = f2b(val);
}

// ---------------- per-node mean aggregation: fp8 gather, fp32 acc, bf16 out ----------------
__global__ __launch_bounds__(256) void k_aggregate(const unsigned char* __restrict__ xq,
        const int* __restrict__ offs, const int* __restrict__ esrc,
        unsigned short* __restrict__ cb) {
    int gidx = blockIdx.x * 256 + threadIdx.x;
    int node = gidx >> 5;
    int lane = threadIdx.x & 31;
    if (node >= N_NODESC) return;
    int beg = offs[node], end = offs[node + 1];
    float a[8];
    #pragma unroll
    for (int j = 0; j < 8; j++) a[j] = 0.f;
    size_t loff = (size_t)lane * 8;
    int e = beg;
    #define ACC8(v) do { \
        floatx2 t0 = __builtin_amdgcn_cvt_pk_f32_fp8((v).x, false); \
        floatx2 t1 = __builtin_amdgcn_cvt_pk_f32_fp8((v).x, true);  \
        floatx2 t2 = __builtin_amdgcn_cvt_pk_f32_fp8((v).y, false); \
        floatx2 t3 = __builtin_amdgcn_cvt_pk_f32_fp8((v).y, true);  \
        a[0] += t0.x; a[1] += t0.y; a[2] += t1.x; a[3] += t1.y;     \
        a[4] += t2.x; a[5] += t2.y; a[6] += t3.x; a[7] += t3.y;     \
    } while (0)
    for (; e + 8 <= end; e += 8) {
        int sidx[8];
        #pragma unroll
        for (int j = 0; j < 8; j++) sidx[j] = esrc[e + j];
        uint2 v[8];
        #pragma unroll
        for (int j = 0; j < 8; j++)
            v[j] = *(const uint2*)(xq + (size_t)sidx[j] * HIDC + loff);
        #pragma unroll
        for (int j = 0; j < 8; j++) ACC8(v[j]);
    }
    if (e + 4 <= end) {
        int sidx[4];
        #pragma unroll
        for (int j = 0; j < 4; j++) sidx[j] = esrc[e + j];
        uint2 v[4];
        #pragma unroll
        for (int j = 0; j < 4; j++)
            v[j] = *(const uint2*)(xq + (size_t)sidx[j] * HIDC + loff);
        #pragma unroll
        for (int j = 0; j < 4; j++) ACC8(v[j]);
        e += 4;
    }
    for (; e < end; e++) {
        uint2 v = *(const uint2*)(xq + (size_t)esrc[e] * HIDC + loff);
        ACC8(v);
    }
    #undef ACC8
    float w = 1.0f / (float)max(end - beg, 1);
    uint4 o;
    o.x = pkb(a[0] * w, a[1] * w);
    o.y = pkb(a[2] * w, a[3] * w);
    o.z = pkb(a[4] * w, a[5] * w);
    o.w = pkb(a[6] * w, a[7] * w);
    *(uint4*)(cb + (size_t)node * HIDC + loff) = o;
}

// ---------------- layer GEMM: depth-4 A / depth-2 B register pipeline ----------------
// Block = 32 rows x 256 cols, 4 waves (wave wn -> cols wn*64..+63), K=512 (xb rows | cb rows).
// __launch_bounds__(256,4): VGPR cap 128 so the compiler can HOLD the pipeline buffers
// (round-8 regression: default budget 52 VGPR silently deleted the prefetch).
__global__ __launch_bounds__(256, 4) void k_lgemm(unsigned short* __restrict__ xb,
        const unsigned short* __restrict__ cbr, const unsigned short* __restrict__ wb,
        const float* __restrict__ bias, unsigned char* __restrict__ xq) {
    __shared__ float rs[32];
    int tid = threadIdx.x;
    int wn = tid >> 6;
    int lane = tid & 63;
    int quad = lane >> 4;
    int l15 = lane & 15;
    int row0 = blockIdx.x * 32;

    floatx4 acc[2][4];
    #pragma unroll
    for (int mt = 0; mt < 2; mt++)
        #pragma unroll
        for (int n = 0; n < 4; n++)
            acc[mt][n] = (floatx4){0.f, 0.f, 0.f, 0.f};

    // per-lane A base: row (row0 + mt*16 + l15), column chunk quad*8 within each 32-col step
    const unsigned short* a0p = xb  + (size_t)(row0 + l15) * HIDC + quad * 8;        // mt=0
    const unsigned short* a1p = xb  + (size_t)(row0 + 16 + l15) * HIDC + quad * 8;   // mt=1
    const unsigned short* c0p = cbr + (size_t)(row0 + l15) * HIDC + quad * 8;
    const unsigned short* c1p = cbr + (size_t)(row0 + 16 + l15) * HIDC + quad * 8;
    const unsigned short* bp  = wb + ((size_t)(wn * 4) * 64 + lane) * 8;             // step stride 8192

    short8 Abuf[4][2];   // depth-4 A pipeline
    short8 Bbuf[2][4];   // depth-2 B pipeline

    // A source for step ks (0..15): ks<8 -> xb at col ks*32, else cb at col (ks-8)*32
    #define LOAD_A(slot, ks) do { \
        if ((ks) < 8) { \
            Abuf[slot][0] = *(const short8*)(a0p + (ks) * 32); \
            Abuf[slot][1] = *(const short8*)(a1p + (ks) * 32); \
        } else { \
            Abuf[slot][0] = *(const short8*)(c0p + ((ks) - 8) * 32); \
            Abuf[slot][1] = *(const short8*)(c1p + ((ks) - 8) * 32); \
        } \
    } while (0)
    #define LOAD_B(slot, ks) do { \
        const unsigned short* wp_ = bp + (size_t)(ks) * 8192; \
        Bbuf[slot][0] = *(const short8*)(wp_); \
        Bbuf[slot][1] = *(const short8*)(wp_ + 512); \
        Bbuf[slot][2] = *(const short8*)(wp_ + 1024); \
        Bbuf[slot][3] = *(const short8*)(wp_ + 1536); \
    } while (0)

    LOAD_A(0, 0); LOAD_A(1, 1); LOAD_A(2, 2); LOAD_A(3, 3);
    LOAD_B(0, 0); LOAD_B(1, 1);

    #pragma unroll
    for (int ks = 0; ks < 16; ks++) {
        const int as = ks & 3;
        const int bs = ks & 1;
        #pragma unroll
        for (int mt = 0; mt < 2; mt++)
            #pragma unroll
            for (int n = 0; n < 4; n++)
                acc[mt][n] = __builtin_amdgcn_mfma_f32_16x16x32_bf16(
                    Abuf[as][mt], Bbuf[bs][n], acc[mt][n], 0, 0, 0);
        if (ks + 4 < 16) LOAD_A(as, ks + 4);
        if (ks + 2 < 16) LOAD_B(bs, ks + 2);
    }
    #undef LOAD_A
    #undef LOAD_B

    float bv[4];
    #pragma unroll
    for (int n = 0; n < 4; n++) bv[n] = bias[wn * 64 + n * 16 + l15];
    #pragma unroll
    for (int mt = 0; mt < 2; mt++)
        #pragma unroll
        for (int n = 0; n < 4; n++)
            #pragma unroll
            for (int r = 0; r < 4; r++)
                acc[mt][n][r] += bv[n];

    if (tid < 32) rs[tid] = 0.f;
    __syncthreads();
    #pragma unroll
    for (int mt = 0; mt < 2; mt++) {
        #pragma unroll
        for (int r = 0; r < 4; r++) {
            float p = acc[mt][0][r] * acc[mt][0][r] + acc[mt][1][r] * acc[mt][1][r]
                    + acc[mt][2][r] * acc[mt][2][r] + acc[mt][3][r] * acc[mt][3][r];
            p += __shfl_xor(p, 1);
            p += __shfl_xor(p, 2);
            p += __shfl_xor(p, 4);
            p += __shfl_xor(p, 8);
            if (l15 == 0) atomicAdd(&rs[mt * 16 + quad * 4 + r], p);
        }
    }
    __syncthreads();

    #pragma unroll
    for (int mt = 0; mt < 2; mt++) {
        #pragma unroll
        for (int r = 0; r < 4; r++) {
            int row = row0 + mt * 16 + quad * 4 + r;
            if (row < N_NODESC) {
                float inv = 1.0f / fmaxf(sqrtf(rs[mt * 16 + quad * 4 + r]), EPSV);
                #pragma unroll
                for (int n = 0; n < 4; n++) {
                    int col = wn * 64 + n * 16 + l15;
                    size_t idx = (size_t)row * HIDC + col;
                    float xo = b2f(xb[idx]);
                    float v = fmaxf(acc[mt][n][r] * inv, 0.f);
                    float nv = xo + v;
                    xb[idx] = f2b(nv);
                    xq[idx] = f2q(nv);
                }
            }
        }
    }
}

// ---------------- embed GEMM: depth-2 pipeline, K=128 ----------------
__global__ __launch_bounds__(256, 4) void k_egemm(const float* __restrict__ h,
        const unsigned short* __restrict__ wsw, const float* __restrict__ bias,
        unsigned short* __restrict__ xb, unsigned char* __restrict__ xq) {
    int tid = threadIdx.x;
    int wn = tid >> 6;
    int lane = tid & 63;
    int quad = lane >> 4;
    int l15 = lane & 15;
    int row0 = blockIdx.x * 32;

    floatx4 acc[2][4];
    #pragma unroll
    for (int mt = 0; mt < 2; mt++)
        #pragma unroll
        for (int n = 0; n < 4; n++)
            acc[mt][n] = (floatx4){0.f, 0.f, 0.f, 0.f};

    int r0 = row0 + l15;
    int r1 = row0 + 16 + l15;
    bool ok0 = r0 < N_NODESC, ok1 = r1 < N_NODESC;
    const float* h0 = h + (size_t)r0 * IN_DIMC + quad * 8;
    const float* h1 = h + (size_t)r1 * IN_DIMC + quad * 8;
    const unsigned short* bp = wsw + ((size_t)(wn * 4) * 64 + lane) * 8;

    float4 Af[2][2][2];  // [slot][mt][half]
    short8 Bbuf[2][4];

    #define LOAD_AE(slot, ks) do { \
        Af[slot][0][0] = ok0 ? *(const float4*)(h0 + (ks) * 32)     : (float4){0,0,0,0}; \
        Af[slot][0][1] = ok0 ? *(const float4*)(h0 + (ks) * 32 + 4) : (float4){0,0,0,0}; \
        Af[slot][1][0] = ok1 ? *(const float4*)(h1 + (ks) * 32)     : (float4){0,0,0,0}; \
        Af[slot][1][1] = ok1 ? *(const float4*)(h1 + (ks) * 32 + 4) : (float4){0,0,0,0}; \
    } while (0)
    #define LOAD_BE(slot, ks) do { \
        const unsigned short* wp_ = bp + (size_t)(ks) * 8192; \
        Bbuf[slot][0] = *(const short8*)(wp_); \
        Bbuf[slot][1] = *(const short8*)(wp_ + 512); \
        Bbuf[slot][2] = *(const short8*)(wp_ + 1024); \
        Bbuf[slot][3] = *(const short8*)(wp_ + 1536); \
    } while (0)

    LOAD_AE(0, 0); LOAD_AE(1, 1);
    LOAD_BE(0, 0); LOAD_BE(1, 1);

    #pragma unroll
    for (int ks = 0; ks < 4; ks++) {
        const int s = ks & 1;
        short8 afr[2];
        #pragma unroll
        for (int mt = 0; mt < 2; mt++) {
            uint4 av;
            av.x = pkb(Af[s][mt][0].x, Af[s][mt][0].y);
            av.y = pkb(Af[s][mt][0].z, Af[s][mt][0].w);
            av.z = pkb(Af[s][mt][1].x, Af[s][mt][1].y);
            av.w = pkb(Af[s][mt][1].z, Af[s][mt][1].w);
            afr[mt] = *(short8*)&av;
        }
        #pragma unroll
        for (int mt = 0; mt < 2; mt++)
            #pragma unroll
            for (int n = 0; n < 4; n++)
                acc[mt][n] = __builtin_amdgcn_mfma_f32_16x16x32_bf16(
                    afr[mt], Bbuf[s][n], acc[mt][n], 0, 0, 0);
        if (ks + 2 < 4) { LOAD_AE(s, ks + 2); LOAD_BE(s, ks + 2); }
    }
    #undef LOAD_AE
    #undef LOAD_BE

    float bv[4];
    #pragma unroll
    for (int n = 0; n < 4; n++) bv[n] = bias[wn * 64 + n * 16 + l15];
    #pragma unroll
    for (int mt = 0; mt < 2; mt++) {
        #pragma unroll
        for (int r = 0; r < 4; r++) {
            int row = row0 + mt * 16 + quad * 4 + r;
            if (row < N_NODESC) {
                #pragma unroll
                for (int n = 0; n < 4; n++) {
                    int col = wn * 64 + n * 16 + l15;
                    float v = acc[mt][n][r] + bv[n];
                    size_t idx = (size_t)row * HIDC + col;
                    xb[idx] = f2b(v);
                    xq[idx] = f2q(v);
                }
            }
        }
    }
}

// ---------------- graph mean-pool: 1 block per (graph, 64-col quarter) ----------------
__global__ __launch_bounds__(256) void k_pool(const unsigned short* __restrict__ xb,
        const int* __restrict__ gstart, float* __restrict__ hg) {
    __shared__ float red[256][8];
    int g = blockIdx.x >> 2;
    int cq = blockIdx.x & 3;
    int t = threadIdx.x;
    int cchunk = t & 7;
    int rgrp = t >> 3;
    int col0 = cq * 64 + cchunk * 8;
    int beg = gstart[g], end = gstart[g + 1];
    float a[8];
    #pragma unroll
    for (int j = 0; j < 8; j++) a[j] = 0.f;
    for (int r = beg + rgrp; r < end; r += 32) {
        uint4 v = *(const uint4*)(xb + (size_t)r * HIDC + col0);
        a[0] += blo(v.x); a[1] += bhi(v.x);
        a[2] += blo(v.y); a[3] += bhi(v.y);
        a[4] += blo(v.z); a[5] += bhi(v.z);
        a[6] += blo(v.w); a[7] += bhi(v.w);
    }
    #pragma unroll
    for (int j = 0; j < 8; j++) red[t][j] = a[j];
    __syncthreads();
    for (int d = 16; d >= 1; d >>= 1) {
        if (rgrp < d) {
            #pragma unroll
            for (int j = 0; j < 8; j++) red[t][j] += red[t + d * 8][j];
        }
        __syncthreads();
    }
    if (rgrp == 0) {
        float inv = 1.0f / (float)max(end - beg, 1);
        #pragma unroll
        for (int j = 0; j < 8; j++)
            hg[g * HIDC + col0 + j] = red[t][j] * inv;
    }
}

// ---------------- readout ----------------
__global__ __launch_bounds__(256) void k_readout(const float* __restrict__ hg,
        const float* __restrict__ ppos, const float* __restrict__ pneg,
        const float* __restrict__ wfc, float* __restrict__ out) {
    __shared__ float red[256];
    __shared__ float ss[10];
    int t = threadIdx.x;
    int g = blockIdx.x;
    float hgv = hg[g * HIDC + t];
    for (int p = 0; p < 10; p++) {
        const float* P = (p < 5) ? (ppos + p * HIDC) : (pneg + (p - 5) * HIDC);
        float d = hgv - P[t];
        red[t] = d * d;
        __syncthreads();
        for (int s2 = 128; s2 > 0; s2 >>= 1) {
            if (t < s2) red[t] += red[t + s2];
            __syncthreads();
        }
        if (t == 0) {
            float dd = red[0];
            ss[p] = logf((dd + 1.0f) / (dd + EPSV));
        }
        __syncthreads();
    }
    if (t == 0) {
        float y = 0.f;
        #pragma unroll
        for (int p = 0; p < 10; p++) y += ss[p] * wfc[p];
        out[g] = 1.0f / (1.0f + expf(-y));
    }
}

extern "C" void kernel_launch(void* const* d_in, const int* in_sizes, int n_in,
                              void* d_out, int out_size, void* d_ws, size_t ws_size,
                              hipStream_t stream) {
    const float* h    = (const float*)d_in[0];
    const int*   src  = (const int*)d_in[1];
    const int*   dst  = (const int*)d_in[2];
    const int*   gid  = (const int*)d_in[3];
    const float* Wemb = (const float*)d_in[4];
    const float* bemb = (const float*)d_in[5];
    const float* Ws   = (const float*)d_in[6];
    const float* bs   = (const float*)d_in[7];
    const float* ppos = (const float*)d_in[8];
    const float* pneg = (const float*)d_in[9];
    const float* wfc  = (const float*)d_in[10];
    float* out = (float*)d_out;

    char* ws = (char*)d_ws;
    size_t off = 0;
    auto alloc = [&](size_t bytes) {
        void* p = ws + off;
        off += (bytes + 255) & ~(size_t)255;
        return p;
    };
    unsigned short* xb  = (unsigned short*)alloc((size_t)NPAD * HIDC * 2);  // bf16 row-major
    unsigned char*  xq  = (unsigned char*)alloc((size_t)NPAD * HIDC);       // fp8 shadow
    unsigned short* cb  = (unsigned short*)alloc((size_t)NPAD * HIDC * 2);  // bf16 row-major
    unsigned short* wsw = (unsigned short*)alloc((size_t)(IN_DIMC * HIDC + N_LAYERSC * 2 * HIDC * HIDC) * 2);
    int*   deg    = (int*)alloc((size_t)N_NODESC * 4);
    int*   offs   = (int*)alloc((size_t)(N_NODESC + 1) * 4);
    int*   cursor = (int*)alloc((size_t)N_NODESC * 4);
    int*   esrc   = (int*)alloc((size_t)N_EDGESC * 4);
    int*   bsum   = (int*)alloc((size_t)SCAN_BLK * 4);
    int*   boff   = (int*)alloc((size_t)SCAN_BLK * 4);
    int*   gstart = (int*)alloc((size_t)(N_GRAPHSC + 1) * 4);
    float* hg     = (float*)alloc((size_t)N_GRAPHSC * HIDC * 4);
    (void)ws_size; (void)in_sizes; (void)n_in; (void)out_size;

    hipMemsetAsync(deg, 0, (size_t)N_NODESC * 4, stream);

    const int WTOT = IN_DIMC * HIDC + N_LAYERSC * 2 * HIDC * HIDC; // 557056
    k_wconv<<<(WTOT + 255) / 256, 256, 0, stream>>>(Wemb, Ws, wsw);
    k_count<<<(N_EDGESC + 255) / 256, 256, 0, stream>>>(dst, deg);
    k_gbounds<<<1, 128, 0, stream>>>(gid, gstart);
    k_scanA<<<SCAN_BLK, 256, 0, stream>>>(deg, bsum);
    k_scanB<<<1, 256, 0, stream>>>(bsum, boff);
    k_scanC<<<SCAN_BLK, 256, 0, stream>>>(deg, boff, offs, cursor);
    k_scatter<<<(N_EDGESC + 255) / 256, 256, 0, stream>>>(src, dst, cursor, esrc);

    const int GBLK = NPAD / 32; // 1564
    k_egemm<<<GBLK, 256, 0, stream>>>(h, wsw, bemb, xb, xq);

    for (int l = 0; l < N_LAYERSC; l++) {
        k_aggregate<<<(N_NODESC * 32 + 255) / 256, 256, 0, stream>>>(xq, offs, esrc, cb);
        k_lgemm<<<GBLK, 256, 0, stream>>>(
            xb, cb,
            wsw + IN_DIMC * HIDC + (size_t)l * 2 * HIDC * HIDC,
            bs + (size_t)l * HIDC, xq);
    }
    k_pool<<<N_GRAPHSC * 4, 256, 0, stream>>>(xb, gstart, hg);
    k_readout<<<N_GRAPHSC, 256, 0, stream>>>(hg, ppos, pneg, wfc, out);
}

// Round 10
// 503.483 us; speedup vs baseline: 1.3845x; 1.1196x over previous
//
#include <hip/hip_runtime.h>
#include <math.h>

#define N_NODESC 50000
#define NPAD 50048              // 782 * 64
#define N_EDGESC 800000
#define N_GRAPHSC 64
#define IN_DIMC 128
#define HIDC 256
#define N_LAYERSC 4
#define EPSV 1e-12f

#define SCAN_BLK 196  // ceil(50000/256)

typedef __attribute__((ext_vector_type(8))) short short8;
typedef __attribute__((ext_vector_type(4))) float floatx4;
typedef __attribute__((ext_vector_type(2))) float floatx2;

__device__ __forceinline__ unsigned short f2b(float f) {
    union { float f; unsigned u; } v; v.f = f;
    unsigned r = v.u + 0x7FFFu + ((v.u >> 16) & 1u);
    return (unsigned short)(r >> 16);
}
__device__ __forceinline__ float blo(unsigned u) { return __uint_as_float(u << 16); }
__device__ __forceinline__ float bhi(unsigned u) { return __uint_as_float(u & 0xFFFF0000u); }
__device__ __forceinline__ unsigned pkb(float a, float b) {
    return (unsigned)f2b(a) | ((unsigned)f2b(b) << 16);
}
__device__ __forceinline__ float b2f(unsigned short s) {
    return __uint_as_float((unsigned)s << 16);
}
__device__ __forceinline__ unsigned char f2q(float v) {
    return (unsigned char)(__builtin_amdgcn_cvt_pk_fp8_f32(v, v, 0, false) & 0xFF);
}
// async global->LDS, 16B per lane; lds base must be wave-uniform
__device__ __forceinline__ void ldscp16(const void* g, void* l) {
    __builtin_amdgcn_global_load_lds(
        (const __attribute__((address_space(1))) unsigned int*)g,
        (__attribute__((address_space(3))) unsigned int*)l, 16, 0, 0);
}

// ---------------- degree count ----------------
__global__ void k_count(const int* __restrict__ dst, int* __restrict__ deg) {
    int e = blockIdx.x * blockDim.x + threadIdx.x;
    if (e < N_EDGESC) atomicAdd(&deg[dst[e]], 1);
}

// ---------------- graph boundaries via binary search (gid sorted) ----------------
__global__ __launch_bounds__(128) void k_gbounds(const int* __restrict__ gid,
        int* __restrict__ gstart) {
    int g = threadIdx.x;
    if (g > N_GRAPHSC) return;
    int lo = 0, hi = N_NODESC;
    while (lo < hi) {
        int mid = (lo + hi) >> 1;
        if (gid[mid] < g) lo = mid + 1; else hi = mid;
    }
    gstart[g] = lo;
}

// ---------------- hierarchical scan ----------------
__global__ __launch_bounds__(256) void k_scanA(const int* __restrict__ deg,
        int* __restrict__ bsum) {
    __shared__ int s[256];
    int t = threadIdx.x;
    int i = blockIdx.x * 256 + t;
    s[t] = (i < N_NODESC) ? deg[i] : 0;
    __syncthreads();
    for (int d = 128; d > 0; d >>= 1) {
        if (t < d) s[t] += s[t + d];
        __syncthreads();
    }
    if (t == 0) bsum[blockIdx.x] = s[0];
}

__global__ __launch_bounds__(256) void k_scanB(const int* __restrict__ bsum,
        int* __restrict__ boff) {
    __shared__ int s[256];
    int t = threadIdx.x;
    int v = (t < SCAN_BLK) ? bsum[t] : 0;
    s[t] = v;
    __syncthreads();
    for (int d = 1; d < 256; d <<= 1) {
        int u = (t >= d) ? s[t - d] : 0;
        __syncthreads();
        s[t] += u;
        __syncthreads();
    }
    if (t < SCAN_BLK) boff[t] = s[t] - v;
}

__global__ __launch_bounds__(256) void k_scanC(const int* __restrict__ deg,
        const int* __restrict__ boff, int* __restrict__ offs, int* __restrict__ cursor) {
    __shared__ int s[256];
    int t = threadIdx.x;
    int i = blockIdx.x * 256 + t;
    int v = (i < N_NODESC) ? deg[i] : 0;
    s[t] = v;
    __syncthreads();
    for (int d = 1; d < 256; d <<= 1) {
        int u = (t >= d) ? s[t - d] : 0;
        __syncthreads();
        s[t] += u;
        __syncthreads();
    }
    int excl = s[t] - v + boff[blockIdx.x];
    if (i < N_NODESC) {
        offs[i] = excl;
        cursor[i] = excl;
        if (i == N_NODESC - 1) offs[N_NODESC] = excl + v;
    }
}

// ---------------- scatter edges into CSR buckets ----------------
__global__ void k_scatter(const int* __restrict__ src, const int* __restrict__ dst,
        int* __restrict__ cursor, int* __restrict__ esrc) {
    int e = blockIdx.x * blockDim.x + threadIdx.x;
    if (e < N_EDGESC) {
        int d = dst[e];
        int pos = atomicAdd(&cursor[d], 1);
        esrc[pos] = src[e];
    }
}

// ---------------- weight convert + swizzle to MFMA B-fragment order ----------------
__global__ __launch_bounds__(256) void k_wconv(const float* __restrict__ Wemb,
        const float* __restrict__ Ws, unsigned short* __restrict__ wsw) {
    int idx = blockIdx.x * 256 + threadIdx.x;
    const int EMB = IN_DIMC * HIDC;           // 32768
    const int LYR = 2 * HIDC * HIDC;          // 131072
    if (idx >= EMB + N_LAYERSC * LYR) return;
    float val; int k, n; unsigned short* basep;
    if (idx < EMB) {
        k = idx >> 8; n = idx & 255;
        val = Wemb[idx];
        basep = wsw;
    } else {
        int r = idx - EMB;
        int l = r >> 17;
        int r2 = r & (LYR - 1);
        k = r2 >> 8; n = r2 & 255;
        val = Ws[r];
        basep = wsw + EMB + l * LYR;
    }
    int off = (((k >> 5) * 16 + (n >> 4)) * 64 + ((((k >> 3) & 3) << 4) | (n & 15))) * 8 + (k & 7);
    basep[off] = f2b(val);
}

// ---------------- per-node mean aggregation: fp8 gather, fp32 acc, bf16 out ----------------
__global__ __launch_bounds__(256) void k_aggregate(const unsigned char* __restrict__ xq,
        const int* __restrict__ offs, const int* __restrict__ esrc,
        unsigned short* __restrict__ cb) {
    int gidx = blockIdx.x * 256 + threadIdx.x;
    int node = gidx >> 5;
    int lane = threadIdx.x & 31;
    if (node >= N_NODESC) return;
    int beg = offs[node], end = offs[node + 1];
    float a[8];
    #pragma unroll
    for (int j = 0; j < 8; j++) a[j] = 0.f;
    size_t loff = (size_t)lane * 8;
    int e = beg;
    #define ACC8(v) do { \
        floatx2 t0 = __builtin_amdgcn_cvt_pk_f32_fp8((v).x, false); \
        floatx2 t1 = __builtin_amdgcn_cvt_pk_f32_fp8((v).x, true);  \
        floatx2 t2 = __builtin_amdgcn_cvt_pk_f32_fp8((v).y, false); \
        floatx2 t3 = __builtin_amdgcn_cvt_pk_f32_fp8((v).y, true);  \
        a[0] += t0.x; a[1] += t0.y; a[2] += t1.x; a[3] += t1.y;     \
        a[4] += t2.x; a[5] += t2.y; a[6] += t3.x; a[7] += t3.y;     \
    } while (0)
    for (; e + 8 <= end; e += 8) {
        int sidx[8];
        #pragma unroll
        for (int j = 0; j < 8; j++) sidx[j] = esrc[e + j];
        uint2 v[8];
        #pragma unroll
        for (int j = 0; j < 8; j++)
            v[j] = *(const uint2*)(xq + (size_t)sidx[j] * HIDC + loff);
        #pragma unroll
        for (int j = 0; j < 8; j++) ACC8(v[j]);
    }
    if (e + 4 <= end) {
        int sidx[4];
        #pragma unroll
        for (int j = 0; j < 4; j++) sidx[j] = esrc[e + j];
        uint2 v[4];
        #pragma unroll
        for (int j = 0; j < 4; j++)
            v[j] = *(const uint2*)(xq + (size_t)sidx[j] * HIDC + loff);
        #pragma unroll
        for (int j = 0; j < 4; j++) ACC8(v[j]);
        e += 4;
    }
    for (; e < end; e++) {
        uint2 v = *(const uint2*)(xq + (size_t)esrc[e] * HIDC + loff);
        ACC8(v);
    }
    #undef ACC8
    float w = 1.0f / (float)max(end - beg, 1);
    uint4 o;
    o.x = pkb(a[0] * w, a[1] * w);
    o.y = pkb(a[2] * w, a[3] * w);
    o.z = pkb(a[4] * w, a[5] * w);
    o.w = pkb(a[6] * w, a[7] * w);
    *(uint4*)(cb + (size_t)node * HIDC + loff) = o;
}

// ---------------- layer GEMM: A-panel in LDS via global_load_lds, 64-row blocks ----------------
// Block = 64 rows x 256 cols, 4 waves (wave w -> cols w*64..+63, all 4 m-tiles).
// Phase p (p=0: xb cols 0..255, p=1: cb): stage 64x512B panel into 32KB LDS (async,
// XOR-swizzled 16B chunks: phys = logical ^ (row&15) -> conflict-free frag reads),
// then 8 K-steps of ds_read_b128(A) + global(B, L2) + 16 MFMA.
__global__ __launch_bounds__(256, 4) void k_lgemm(unsigned short* __restrict__ xb,
        const unsigned short* __restrict__ cbr, const unsigned short* __restrict__ wb,
        const float* __restrict__ bias, unsigned char* __restrict__ xq) {
    __shared__ unsigned short As[16384];   // 32 KB panel
    __shared__ float rs[64];
    int tid = threadIdx.x;
    int w = tid >> 6;
    int lane = tid & 63;
    int quad = lane >> 4;
    int l15 = lane & 15;
    int row0 = blockIdx.x * 64;

    floatx4 acc[4][4];
    #pragma unroll
    for (int mt = 0; mt < 4; mt++)
        #pragma unroll
        for (int n = 0; n < 4; n++)
            acc[mt][n] = (floatx4){0.f, 0.f, 0.f, 0.f};

    const unsigned short* bp = wb + ((size_t)(w * 4) * 64 + lane) * 8;  // step stride 8192

    // per-lane staging source mapping (constant across phases)
    int sboff = (tid >> 6) * 8192 + lane * 16;  // this lane's first LDS byte (i=0)
    #pragma unroll
    for (int phase = 0; phase < 2; phase++) {
        const unsigned short* srcb = (phase == 0) ? (const unsigned short*)xb : cbr;
        if (phase == 1) __syncthreads();   // all phase-0 reads done before overwrite
        #pragma unroll
        for (int i = 0; i < 8; i++) {
            int ldsoff = sboff + i * 1024;         // bytes
            int r = ldsoff >> 9;                   // row 0..63
            int ch = (ldsoff & 511) >> 4;          // physical 16B chunk 0..31
            int lc = ch ^ (r & 15);                // logical chunk
            const unsigned short* g = srcb + (size_t)(row0 + r) * HIDC + lc * 8;
            ldscp16(g, &As[w * 4096 + i * 512]);   // lds base wave-uniform (halves)
        }
        __syncthreads();   // drains vmcnt -> panel visible

        #pragma unroll
        for (int ks = 0; ks < 8; ks++) {
            short8 afr[4], bfr[4];
            #pragma unroll
            for (int mt = 0; mt < 4; mt++) {
                int row = mt * 16 + l15;
                int phys = ((ks << 2) | quad) ^ l15;
                afr[mt] = *(const short8*)&As[row * 256 + phys * 8];
            }
            const unsigned short* wp = bp + (size_t)(phase * 8 + ks) * 8192;
            #pragma unroll
            for (int n = 0; n < 4; n++)
                bfr[n] = *(const short8*)(wp + n * 512);
            #pragma unroll
            for (int mt = 0; mt < 4; mt++)
                #pragma unroll
                for (int n = 0; n < 4; n++)
                    acc[mt][n] = __builtin_amdgcn_mfma_f32_16x16x32_bf16(
                        afr[mt], bfr[n], acc[mt][n], 0, 0, 0);
        }
    }

    float bv[4];
    #pragma unroll
    for (int n = 0; n < 4; n++) bv[n] = bias[w * 64 + n * 16 + l15];
    #pragma unroll
    for (int mt = 0; mt < 4; mt++)
        #pragma unroll
        for (int n = 0; n < 4; n++)
            #pragma unroll
            for (int r = 0; r < 4; r++)
                acc[mt][n][r] += bv[n];

    // row L2-norm across 4 col-waves
    __syncthreads();
    if (tid < 64) rs[tid] = 0.f;
    __syncthreads();
    #pragma unroll
    for (int mt = 0; mt < 4; mt++) {
        #pragma unroll
        for (int r = 0; r < 4; r++) {
            float p = acc[mt][0][r] * acc[mt][0][r] + acc[mt][1][r] * acc[mt][1][r]
                    + acc[mt][2][r] * acc[mt][2][r] + acc[mt][3][r] * acc[mt][3][r];
            p += __shfl_xor(p, 1);
            p += __shfl_xor(p, 2);
            p += __shfl_xor(p, 4);
            p += __shfl_xor(p, 8);
            if (l15 == 0) atomicAdd(&rs[mt * 16 + quad * 4 + r], p);
        }
    }
    __syncthreads();

    #pragma unroll
    for (int mt = 0; mt < 4; mt++) {
        #pragma unroll
        for (int r = 0; r < 4; r++) {
            int row = row0 + mt * 16 + quad * 4 + r;
            if (row < N_NODESC) {
                float inv = 1.0f / fmaxf(sqrtf(rs[mt * 16 + quad * 4 + r]), EPSV);
                #pragma unroll
                for (int n = 0; n < 4; n++) {
                    int col = w * 64 + n * 16 + l15;
                    size_t idx = (size_t)row * HIDC + col;
                    float xo = b2f(xb[idx]);
                    float v = fmaxf(acc[mt][n][r] * inv, 0.f);
                    float nv = xo + v;
                    xb[idx] = f2b(nv);
                    xq[idx] = f2q(nv);
                }
            }
        }
    }
}

// ---------------- embed GEMM: 32-row blocks, direct fp32 frag loads ----------------
__global__ __launch_bounds__(256, 4) void k_egemm(const float* __restrict__ h,
        const unsigned short* __restrict__ wsw, const float* __restrict__ bias,
        unsigned short* __restrict__ xb, unsigned char* __restrict__ xq) {
    int tid = threadIdx.x;
    int wn = tid >> 6;
    int lane = tid & 63;
    int quad = lane >> 4;
    int l15 = lane & 15;
    int row0 = blockIdx.x * 32;

    floatx4 acc[2][4];
    #pragma unroll
    for (int mt = 0; mt < 2; mt++)
        #pragma unroll
        for (int n = 0; n < 4; n++)
            acc[mt][n] = (floatx4){0.f, 0.f, 0.f, 0.f};

    int r0 = row0 + l15;
    int r1 = row0 + 16 + l15;
    bool ok0 = r0 < N_NODESC, ok1 = r1 < N_NODESC;
    const float* h0 = h + (size_t)r0 * IN_DIMC + quad * 8;
    const float* h1 = h + (size_t)r1 * IN_DIMC + quad * 8;
    const unsigned short* bp = wsw + ((size_t)(wn * 4) * 64 + lane) * 8;

    #pragma unroll
    for (int ks = 0; ks < 4; ks++) {
        float4 f00 = ok0 ? *(const float4*)(h0 + ks * 32)     : (float4){0,0,0,0};
        float4 f01 = ok0 ? *(const float4*)(h0 + ks * 32 + 4) : (float4){0,0,0,0};
        float4 f10 = ok1 ? *(const float4*)(h1 + ks * 32)     : (float4){0,0,0,0};
        float4 f11 = ok1 ? *(const float4*)(h1 + ks * 32 + 4) : (float4){0,0,0,0};
        short8 afr[2], bfr[4];
        uint4 av;
        av.x = pkb(f00.x, f00.y); av.y = pkb(f00.z, f00.w);
        av.z = pkb(f01.x, f01.y); av.w = pkb(f01.z, f01.w);
        afr[0] = *(short8*)&av;
        av.x = pkb(f10.x, f10.y); av.y = pkb(f10.z, f10.w);
        av.z = pkb(f11.x, f11.y); av.w = pkb(f11.z, f11.w);
        afr[1] = *(short8*)&av;
        const unsigned short* wp = bp + (size_t)ks * 8192;
        #pragma unroll
        for (int n = 0; n < 4; n++)
            bfr[n] = *(const short8*)(wp + n * 512);
        #pragma unroll
        for (int mt = 0; mt < 2; mt++)
            #pragma unroll
            for (int n = 0; n < 4; n++)
                acc[mt][n] = __builtin_amdgcn_mfma_f32_16x16x32_bf16(
                    afr[mt], bfr[n], acc[mt][n], 0, 0, 0);
    }

    float bv[4];
    #pragma unroll
    for (int n = 0; n < 4; n++) bv[n] = bias[wn * 64 + n * 16 + l15];
    #pragma unroll
    for (int mt = 0; mt < 2; mt++) {
        #pragma unroll
        for (int r = 0; r < 4; r++) {
            int row = row0 + mt * 16 + quad * 4 + r;
            if (row < N_NODESC) {
                #pragma unroll
                for (int n = 0; n < 4; n++) {
                    int col = wn * 64 + n * 16 + l15;
                    float v = acc[mt][n][r] + bv[n];
                    size_t idx = (size_t)row * HIDC + col;
                    xb[idx] = f2b(v);
                    xq[idx] = f2q(v);
                }
            }
        }
    }
}

// ---------------- graph mean-pool: 1 block per (graph, 64-col quarter) ----------------
__global__ __launch_bounds__(256) void k_pool(const unsigned short* __restrict__ xb,
        const int* __restrict__ gstart, float* __restrict__ hg) {
    __shared__ float red[256][8];
    int g = blockIdx.x >> 2;
    int cq = blockIdx.x & 3;
    int t = threadIdx.x;
    int cchunk = t & 7;
    int rgrp = t >> 3;
    int col0 = cq * 64 + cchunk * 8;
    int beg = gstart[g], end = gstart[g + 1];
    float a[8];
    #pragma unroll
    for (int j = 0; j < 8; j++) a[j] = 0.f;
    for (int r = beg + rgrp; r < end; r += 32) {
        uint4 v = *(const uint4*)(xb + (size_t)r * HIDC + col0);
        a[0] += blo(v.x); a[1] += bhi(v.x);
        a[2] += blo(v.y); a[3] += bhi(v.y);
        a[4] += blo(v.z); a[5] += bhi(v.z);
        a[6] += blo(v.w); a[7] += bhi(v.w);
    }
    #pragma unroll
    for (int j = 0; j < 8; j++) red[t][j] = a[j];
    __syncthreads();
    for (int d = 16; d >= 1; d >>= 1) {
        if (rgrp < d) {
            #pragma unroll
            for (int j = 0; j < 8; j++) red[t][j] += red[t + d * 8][j];
        }
        __syncthreads();
    }
    if (rgrp == 0) {
        float inv = 1.0f / (float)max(end - beg, 1);
        #pragma unroll
        for (int j = 0; j < 8; j++)
            hg[g * HIDC + col0 + j] = red[t][j] * inv;
    }
}

// ---------------- readout ----------------
__global__ __launch_bounds__(256) void k_readout(const float* __restrict__ hg,
        const float* __restrict__ ppos, const float* __restrict__ pneg,
        const float* __restrict__ wfc, float* __restrict__ out) {
    __shared__ float red[256];
    __shared__ float ss[10];
    int t = threadIdx.x;
    int g = blockIdx.x;
    float hgv = hg[g * HIDC + t];
    for (int p = 0; p < 10; p++) {
        const float* P = (p < 5) ? (ppos + p * HIDC) : (pneg + (p - 5) * HIDC);
        float d = hgv - P[t];
        red[t] = d * d;
        __syncthreads();
        for (int s2 = 128; s2 > 0; s2 >>= 1) {
            if (t < s2) red[t] += red[t + s2];
            __syncthreads();
        }
        if (t == 0) {
            float dd = red[0];
            ss[p] = logf((dd + 1.0f) / (dd + EPSV));
        }
        __syncthreads();
    }
    if (t == 0) {
        float y = 0.f;
        #pragma unroll
        for (int p = 0; p < 10; p++) y += ss[p] * wfc[p];
        out[g] = 1.0f / (1.0f + expf(-y));
    }
}

extern "C" void kernel_launch(void* const* d_in, const int* in_sizes, int n_in,
                              void* d_out, int out_size, void* d_ws, size_t ws_size,
                              hipStream_t stream) {
    const float* h    = (const float*)d_in[0];
    const int*   src  = (const int*)d_in[1];
    const int*   dst  = (const int*)d_in[2];
    const int*   gid  = (const int*)d_in[3];
    const float* Wemb = (const float*)d_in[4];
    const float* bemb = (const float*)d_in[5];
    const float* Ws   = (const float*)d_in[6];
    const float* bs   = (const float*)d_in[7];
    const float* ppos = (const float*)d_in[8];
    const float* pneg = (const float*)d_in[9];
    const float* wfc  = (const float*)d_in[10];
    float* out = (float*)d_out;

    char* ws = (char*)d_ws;
    size_t off = 0;
    auto alloc = [&](size_t bytes) {
        void* p = ws + off;
        off += (bytes + 255) & ~(size_t)255;
        return p;
    };
    unsigned short* xb  = (unsigned short*)alloc((size_t)NPAD * HIDC * 2);  // bf16 row-major
    unsigned char*  xq  = (unsigned char*)alloc((size_t)NPAD * HIDC);       // fp8 shadow
    unsigned short* cb  = (unsigned short*)alloc((size_t)NPAD * HIDC * 2);  // bf16 row-major
    unsigned short* wsw = (unsigned short*)alloc((size_t)(IN_DIMC * HIDC + N_LAYERSC * 2 * HIDC * HIDC) * 2);
    int*   deg    = (int*)alloc((size_t)N_NODESC * 4);
    int*   offs   = (int*)alloc((size_t)(N_NODESC + 1) * 4);
    int*   cursor = (int*)alloc((size_t)N_NODESC * 4);
    int*   esrc   = (int*)alloc((size_t)N_EDGESC * 4);
    int*   bsum   = (int*)alloc((size_t)SCAN_BLK * 4);
    int*   boff   = (int*)alloc((size_t)SCAN_BLK * 4);
    int*   gstart = (int*)alloc((size_t)(N_GRAPHSC + 1) * 4);
    float* hg     = (float*)alloc((size_t)N_GRAPHSC * HIDC * 4);
    (void)ws_size; (void)in_sizes; (void)n_in; (void)out_size;

    hipMemsetAsync(deg, 0, (size_t)N_NODESC * 4, stream);

    const int WTOT = IN_DIMC * HIDC + N_LAYERSC * 2 * HIDC * HIDC; // 557056
    k_wconv<<<(WTOT + 255) / 256, 256, 0, stream>>>(Wemb, Ws, wsw);
    k_count<<<(N_EDGESC + 255) / 256, 256, 0, stream>>>(dst, deg);
    k_gbounds<<<1, 128, 0, stream>>>(gid, gstart);
    k_scanA<<<SCAN_BLK, 256, 0, stream>>>(deg, bsum);
    k_scanB<<<1, 256, 0, stream>>>(bsum, boff);
    k_scanC<<<SCAN_BLK, 256, 0, stream>>>(deg, boff, offs, cursor);
    k_scatter<<<(N_EDGESC + 255) / 256, 256, 0, stream>>>(src, dst, cursor, esrc);

    k_egemm<<<NPAD / 32, 256, 0, stream>>>(h, wsw, bemb, xb, xq);

    for (int l = 0; l < N_LAYERSC; l++) {
        k_aggregate<<<(N_NODESC * 32 + 255) / 256, 256, 0, stream>>>(xq, offs, esrc, cb);
        k_lgemm<<<NPAD / 64, 256, 0, stream>>>(
            xb, cb,
            wsw + IN_DIMC * HIDC + (size_t)l * 2 * HIDC * HIDC,
            bs + (size_t)l * HIDC, xq);
    }
    k_pool<<<N_GRAPHSC * 4, 256, 0, stream>>>(xb, gstart, hg);
    k_readout<<<N_GRAPHSC, 256, 0, stream>>>(hg, ppos, pneg, wfc, out);
}

// Round 11
// 453.458 us; speedup vs baseline: 1.5372x; 1.1103x over previous
//
#include <hip/hip_runtime.h>
#include <math.h>

#define N_NODESC 50000
#define NPAD 50048              // 782 * 64
#define N_EDGESC 800000
#define N_GRAPHSC 64
#define IN_DIMC 128
#define HIDC 256
#define N_LAYERSC 4
#define EPSV 1e-12f

#define NBUCK 196               // buckets of 256 nodes (196*256 = 50176)
#define EPB 4096                // edges per block in bucketing kernels
#define NBLK1 196               // ceil(800000/4096)

typedef __attribute__((ext_vector_type(8))) short short8;
typedef __attribute__((ext_vector_type(4))) float floatx4;
typedef __attribute__((ext_vector_type(2))) float floatx2;

__device__ __forceinline__ unsigned short f2b(float f) {
    union { float f; unsigned u; } v; v.f = f;
    unsigned r = v.u + 0x7FFFu + ((v.u >> 16) & 1u);
    return (unsigned short)(r >> 16);
}
__device__ __forceinline__ float blo(unsigned u) { return __uint_as_float(u << 16); }
__device__ __forceinline__ float bhi(unsigned u) { return __uint_as_float(u & 0xFFFF0000u); }
__device__ __forceinline__ unsigned pkb(float a, float b) {
    return (unsigned)f2b(a) | ((unsigned)f2b(b) << 16);
}
__device__ __forceinline__ float b2f(unsigned short s) {
    return __uint_as_float((unsigned)s << 16);
}
__device__ __forceinline__ unsigned char f2q(float v) {
    return (unsigned char)(__builtin_amdgcn_cvt_pk_fp8_f32(v, v, 0, false) & 0xFF);
}
__device__ __forceinline__ void ldscp16(const void* g, void* l) {
    __builtin_amdgcn_global_load_lds(
        (const __attribute__((address_space(1))) unsigned int*)g,
        (__attribute__((address_space(3))) unsigned int*)l, 16, 0, 0);
}

// ---------------- graph boundaries via binary search (gid sorted) ----------------
__global__ __launch_bounds__(128) void k_gbounds(const int* __restrict__ gid,
        int* __restrict__ gstart) {
    int g = threadIdx.x;
    if (g > N_GRAPHSC) return;
    int lo = 0, hi = N_NODESC;
    while (lo < hi) {
        int mid = (lo + hi) >> 1;
        if (gid[mid] < g) lo = mid + 1; else hi = mid;
    }
    gstart[g] = lo;
}

// ---------------- CSR build, bucketed (bucket = dst>>8) ----------------
// 1) per-bucket edge totals
__global__ __launch_bounds__(256) void k_bcount(const int* __restrict__ dst,
        int* __restrict__ gbcnt) {
    __shared__ int bc[256];
    int t = threadIdx.x;
    bc[t] = 0;
    __syncthreads();
    int e0 = blockIdx.x * EPB;
    for (int i = t; i < EPB; i += 256) {
        int e = e0 + i;
        if (e < N_EDGESC) atomicAdd(&bc[dst[e] >> 8], 1);
    }
    __syncthreads();
    if (t < NBUCK && bc[t] > 0) atomicAdd(&gbcnt[t], bc[t]);
}

// 2) scan bucket totals -> bucket bases + cursors
__global__ __launch_bounds__(256) void k_bscan(const int* __restrict__ gbcnt,
        int* __restrict__ boffB, int* __restrict__ gcurB) {
    __shared__ int s[256];
    int t = threadIdx.x;
    int v = (t < NBUCK) ? gbcnt[t] : 0;
    s[t] = v;
    __syncthreads();
    for (int d = 1; d < 256; d <<= 1) {
        int u = (t >= d) ? s[t - d] : 0;
        __syncthreads();
        s[t] += u;
        __syncthreads();
    }
    if (t < NBUCK) {
        int excl = s[t] - v;
        boffB[t] = excl;
        gcurB[t] = excl;
    }
    if (t == 0) boffB[NBUCK] = N_EDGESC;
}

// 3) bucket-scatter edges as packed (src | dst_local<<16), block-run coalesced
__global__ __launch_bounds__(256) void k_bscatter(const int* __restrict__ src,
        const int* __restrict__ dst, int* __restrict__ gcurB,
        unsigned* __restrict__ ebpack) {
    __shared__ int bc[256];
    __shared__ int cur[256];
    int t = threadIdx.x;
    bc[t] = 0;
    __syncthreads();
    int e0 = blockIdx.x * EPB;
    for (int i = t; i < EPB; i += 256) {
        int e = e0 + i;
        if (e < N_EDGESC) atomicAdd(&bc[dst[e] >> 8], 1);
    }
    __syncthreads();
    if (t < NBUCK)
        cur[t] = (bc[t] > 0) ? atomicAdd(&gcurB[t], bc[t]) : 0;
    __syncthreads();
    for (int i = t; i < EPB; i += 256) {
        int e = e0 + i;
        if (e < N_EDGESC) {
            int d = dst[e];
            int b = d >> 8;
            int pos = atomicAdd(&cur[b], 1);
            ebpack[pos] = (unsigned)src[e] | ((unsigned)(d & 255) << 16);
        }
    }
}

// 4) per-bucket CSR build in LDS; coalesced offs + esrc(ushort) writes
__global__ __launch_bounds__(256) void k_bbuild(const unsigned* __restrict__ ebpack,
        const int* __restrict__ boffB, int* __restrict__ offs,
        unsigned short* __restrict__ esrc) {
    __shared__ int deg[256];
    __shared__ int lofs[256];
    __shared__ unsigned short img[12288];
    int b = blockIdx.x;
    int t = threadIdx.x;
    int bbase = boffB[b];
    int cnt = boffB[b + 1] - bbase;
    deg[t] = 0;
    __syncthreads();
    for (int i = t; i < cnt; i += 256)
        atomicAdd(&deg[ebpack[bbase + i] >> 16], 1);
    __syncthreads();
    int v = deg[t];
    lofs[t] = v;
    __syncthreads();
    for (int d = 1; d < 256; d <<= 1) {
        int u = (t >= d) ? lofs[t - d] : 0;
        __syncthreads();
        lofs[t] += u;
        __syncthreads();
    }
    int excl = lofs[t] - v;
    int node = b * 256 + t;
    if (node < N_NODESC) offs[node] = bbase + excl;
    if (b == NBUCK - 1 && t == 0) offs[N_NODESC] = N_EDGESC;
    deg[t] = excl;   // reuse as cursor
    __syncthreads();
    for (int i = t; i < cnt; i += 256) {
        unsigned p = ebpack[bbase + i];
        int pos = atomicAdd(&deg[p >> 16], 1);
        img[pos] = (unsigned short)(p & 0xFFFF);
    }
    __syncthreads();
    for (int i = t; i < cnt; i += 256)
        esrc[bbase + i] = img[i];
}

// ---------------- weight convert + swizzle to MFMA B-fragment order ----------------
__global__ __launch_bounds__(256) void k_wconv(const float* __restrict__ Wemb,
        const float* __restrict__ Ws, unsigned short* __restrict__ wsw) {
    int idx = blockIdx.x * 256 + threadIdx.x;
    const int EMB = IN_DIMC * HIDC;           // 32768
    const int LYR = 2 * HIDC * HIDC;          // 131072
    if (idx >= EMB + N_LAYERSC * LYR) return;
    float val; int k, n; unsigned short* basep;
    if (idx < EMB) {
        k = idx >> 8; n = idx & 255;
        val = Wemb[idx];
        basep = wsw;
    } else {
        int r = idx - EMB;
        int l = r >> 17;
        int r2 = r & (LYR - 1);
        k = r2 >> 8; n = r2 & 255;
        val = Ws[r];
        basep = wsw + EMB + l * LYR;
    }
    int off = (((k >> 5) * 16 + (n >> 4)) * 64 + ((((k >> 3) & 3) << 4) | (n & 15))) * 8 + (k & 7);
    basep[off] = f2b(val);
}

// ---------------- per-node mean aggregation: fp8 gather, fp32 acc, bf16 out ----------------
__global__ __launch_bounds__(256) void k_aggregate(const unsigned char* __restrict__ xq,
        const int* __restrict__ offs, const unsigned short* __restrict__ esrc,
        unsigned short* __restrict__ cb) {
    int gidx = blockIdx.x * 256 + threadIdx.x;
    int node = gidx >> 5;
    int lane = threadIdx.x & 31;
    if (node >= N_NODESC) return;
    int beg = offs[node], end = offs[node + 1];
    float a[8];
    #pragma unroll
    for (int j = 0; j < 8; j++) a[j] = 0.f;
    size_t loff = (size_t)lane * 8;
    int e = beg;
    #define ACC8(v) do { \
        floatx2 t0 = __builtin_amdgcn_cvt_pk_f32_fp8((v).x, false); \
        floatx2 t1 = __builtin_amdgcn_cvt_pk_f32_fp8((v).x, true);  \
        floatx2 t2 = __builtin_amdgcn_cvt_pk_f32_fp8((v).y, false); \
        floatx2 t3 = __builtin_amdgcn_cvt_pk_f32_fp8((v).y, true);  \
        a[0] += t0.x; a[1] += t0.y; a[2] += t1.x; a[3] += t1.y;     \
        a[4] += t2.x; a[5] += t2.y; a[6] += t3.x; a[7] += t3.y;     \
    } while (0)
    for (; e + 8 <= end; e += 8) {
        int sidx[8];
        #pragma unroll
        for (int j = 0; j < 8; j++) sidx[j] = esrc[e + j];
        uint2 v[8];
        #pragma unroll
        for (int j = 0; j < 8; j++)
            v[j] = *(const uint2*)(xq + (size_t)sidx[j] * HIDC + loff);
        #pragma unroll
        for (int j = 0; j < 8; j++) ACC8(v[j]);
    }
    if (e + 4 <= end) {
        int sidx[4];
        #pragma unroll
        for (int j = 0; j < 4; j++) sidx[j] = esrc[e + j];
        uint2 v[4];
        #pragma unroll
        for (int j = 0; j < 4; j++)
            v[j] = *(const uint2*)(xq + (size_t)sidx[j] * HIDC + loff);
        #pragma unroll
        for (int j = 0; j < 4; j++) ACC8(v[j]);
        e += 4;
    }
    for (; e < end; e++) {
        uint2 v = *(const uint2*)(xq + (size_t)esrc[e] * HIDC + loff);
        ACC8(v);
    }
    #undef ACC8
    float w = 1.0f / (float)max(end - beg, 1);
    uint4 o;
    o.x = pkb(a[0] * w, a[1] * w);
    o.y = pkb(a[2] * w, a[3] * w);
    o.z = pkb(a[4] * w, a[5] * w);
    o.w = pkb(a[6] * w, a[7] * w);
    *(uint4*)(cb + (size_t)node * HIDC + loff) = o;
}

// ---------------- layer GEMM: A-panel in LDS via global_load_lds, 64-row blocks ----------------
__global__ __launch_bounds__(256, 4) void k_lgemm(unsigned short* __restrict__ xb,
        const unsigned short* __restrict__ cbr, const unsigned short* __restrict__ wb,
        const float* __restrict__ bias, unsigned char* __restrict__ xq) {
    __shared__ unsigned short As[16384];   // 32 KB panel
    __shared__ float rs[64];
    int tid = threadIdx.x;
    int w = tid >> 6;
    int lane = tid & 63;
    int quad = lane >> 4;
    int l15 = lane & 15;
    int row0 = blockIdx.x * 64;

    floatx4 acc[4][4];
    #pragma unroll
    for (int mt = 0; mt < 4; mt++)
        #pragma unroll
        for (int n = 0; n < 4; n++)
            acc[mt][n] = (floatx4){0.f, 0.f, 0.f, 0.f};

    const unsigned short* bp = wb + ((size_t)(w * 4) * 64 + lane) * 8;  // step stride 8192

    int sboff = (tid >> 6) * 8192 + lane * 16;
    #pragma unroll
    for (int phase = 0; phase < 2; phase++) {
        const unsigned short* srcb = (phase == 0) ? (const unsigned short*)xb : cbr;
        if (phase == 1) __syncthreads();
        #pragma unroll
        for (int i = 0; i < 8; i++) {
            int ldsoff = sboff + i * 1024;
            int r = ldsoff >> 9;
            int ch = (ldsoff & 511) >> 4;
            int lc = ch ^ (r & 15);
            const unsigned short* g = srcb + (size_t)(row0 + r) * HIDC + lc * 8;
            ldscp16(g, &As[w * 4096 + i * 512]);
        }
        __syncthreads();

        #pragma unroll
        for (int ks = 0; ks < 8; ks++) {
            short8 afr[4], bfr[4];
            #pragma unroll
            for (int mt = 0; mt < 4; mt++) {
                int row = mt * 16 + l15;
                int phys = ((ks << 2) | quad) ^ l15;
                afr[mt] = *(const short8*)&As[row * 256 + phys * 8];
            }
            const unsigned short* wp = bp + (size_t)(phase * 8 + ks) * 8192;
            #pragma unroll
            for (int n = 0; n < 4; n++)
                bfr[n] = *(const short8*)(wp + n * 512);
            #pragma unroll
            for (int mt = 0; mt < 4; mt++)
                #pragma unroll
                for (int n = 0; n < 4; n++)
                    acc[mt][n] = __builtin_amdgcn_mfma_f32_16x16x32_bf16(
                        afr[mt], bfr[n], acc[mt][n], 0, 0, 0);
        }
    }

    float bv[4];
    #pragma unroll
    for (int n = 0; n < 4; n++) bv[n] = bias[w * 64 + n * 16 + l15];
    #pragma unroll
    for (int mt = 0; mt < 4; mt++)
        #pragma unroll
        for (int n = 0; n < 4; n++)
            #pragma unroll
            for (int r = 0; r < 4; r++)
                acc[mt][n][r] += bv[n];

    __syncthreads();
    if (tid < 64) rs[tid] = 0.f;
    __syncthreads();
    #pragma unroll
    for (int mt = 0; mt < 4; mt++) {
        #pragma unroll
        for (int r = 0; r < 4; r++) {
            float p = acc[mt][0][r] * acc[mt][0][r] + acc[mt][1][r] * acc[mt][1][r]
                    + acc[mt][2][r] * acc[mt][2][r] + acc[mt][3][r] * acc[mt][3][r];
            p += __shfl_xor(p, 1);
            p += __shfl_xor(p, 2);
            p += __shfl_xor(p, 4);
            p += __shfl_xor(p, 8);
            if (l15 == 0) atomicAdd(&rs[mt * 16 + quad * 4 + r], p);
        }
    }
    __syncthreads();

    #pragma unroll
    for (int mt = 0; mt < 4; mt++) {
        #pragma unroll
        for (int r = 0; r < 4; r++) {
            int row = row0 + mt * 16 + quad * 4 + r;
            if (row < N_NODESC) {
                float inv = 1.0f / fmaxf(sqrtf(rs[mt * 16 + quad * 4 + r]), EPSV);
                #pragma unroll
                for (int n = 0; n < 4; n++) {
                    int col = w * 64 + n * 16 + l15;
                    size_t idx = (size_t)row * HIDC + col;
                    float xo = b2f(xb[idx]);
                    float v = fmaxf(acc[mt][n][r] * inv, 0.f);
                    float nv = xo + v;
                    xb[idx] = f2b(nv);
                    xq[idx] = f2q(nv);
                }
            }
        }
    }
}

// ---------------- embed GEMM: 32-row blocks, direct fp32 frag loads ----------------
__global__ __launch_bounds__(256, 4) void k_egemm(const float* __restrict__ h,
        const unsigned short* __restrict__ wsw, const float* __restrict__ bias,
        unsigned short* __restrict__ xb, unsigned char* __restrict__ xq) {
    int tid = threadIdx.x;
    int wn = tid >> 6;
    int lane = tid & 63;
    int quad = lane >> 4;
    int l15 = lane & 15;
    int row0 = blockIdx.x * 32;

    floatx4 acc[2][4];
    #pragma unroll
    for (int mt = 0; mt < 2; mt++)
        #pragma unroll
        for (int n = 0; n < 4; n++)
            acc[mt][n] = (floatx4){0.f, 0.f, 0.f, 0.f};

    int r0 = row0 + l15;
    int r1 = row0 + 16 + l15;
    bool ok0 = r0 < N_NODESC, ok1 = r1 < N_NODESC;
    const float* h0 = h + (size_t)r0 * IN_DIMC + quad * 8;
    const float* h1 = h + (size_t)r1 * IN_DIMC + quad * 8;
    const unsigned short* bp = wsw + ((size_t)(wn * 4) * 64 + lane) * 8;

    #pragma unroll
    for (int ks = 0; ks < 4; ks++) {
        float4 f00 = ok0 ? *(const float4*)(h0 + ks * 32)     : (float4){0,0,0,0};
        float4 f01 = ok0 ? *(const float4*)(h0 + ks * 32 + 4) : (float4){0,0,0,0};
        float4 f10 = ok1 ? *(const float4*)(h1 + ks * 32)     : (float4){0,0,0,0};
        float4 f11 = ok1 ? *(const float4*)(h1 + ks * 32 + 4) : (float4){0,0,0,0};
        short8 afr[2], bfr[4];
        uint4 av;
        av.x = pkb(f00.x, f00.y); av.y = pkb(f00.z, f00.w);
        av.z = pkb(f01.x, f01.y); av.w = pkb(f01.z, f01.w);
        afr[0] = *(short8*)&av;
        av.x = pkb(f10.x, f10.y); av.y = pkb(f10.z, f10.w);
        av.z = pkb(f11.x, f11.y); av.w = pkb(f11.z, f11.w);
        afr[1] = *(short8*)&av;
        const unsigned short* wp = bp + (size_t)ks * 8192;
        #pragma unroll
        for (int n = 0; n < 4; n++)
            bfr[n] = *(const short8*)(wp + n * 512);
        #pragma unroll
        for (int mt = 0; mt < 2; mt++)
            #pragma unroll
            for (int n = 0; n < 4; n++)
                acc[mt][n] = __builtin_amdgcn_mfma_f32_16x16x32_bf16(
                    afr[mt], bfr[n], acc[mt][n], 0, 0, 0);
    }

    float bv[4];
    #pragma unroll
    for (int n = 0; n < 4; n++) bv[n] = bias[wn * 64 + n * 16 + l15];
    #pragma unroll
    for (int mt = 0; mt < 2; mt++) {
        #pragma unroll
        for (int r = 0; r < 4; r++) {
            int row = row0 + mt * 16 + quad * 4 + r;
            if (row < N_NODESC) {
                #pragma unroll
                for (int n = 0; n < 4; n++) {
                    int col = wn * 64 + n * 16 + l15;
                    float v = acc[mt][n][r] + bv[n];
                    size_t idx = (size_t)row * HIDC + col;
                    xb[idx] = f2b(v);
                    xq[idx] = f2q(v);
                }
            }
        }
    }
}

// ---------------- graph mean-pool: 1 block per (graph, 64-col quarter) ----------------
__global__ __launch_bounds__(256) void k_pool(const unsigned short* __restrict__ xb,
        const int* __restrict__ gstart, float* __restrict__ hg) {
    __shared__ float red[256][8];
    int g = blockIdx.x >> 2;
    int cq = blockIdx.x & 3;
    int t = threadIdx.x;
    int cchunk = t & 7;
    int rgrp = t >> 3;
    int col0 = cq * 64 + cchunk * 8;
    int beg = gstart[g], end = gstart[g + 1];
    float a[8];
    #pragma unroll
    for (int j = 0; j < 8; j++) a[j] = 0.f;
    for (int r = beg + rgrp; r < end; r += 32) {
        uint4 v = *(const uint4*)(xb + (size_t)r * HIDC + col0);
        a[0] += blo(v.x); a[1] += bhi(v.x);
        a[2] += blo(v.y); a[3] += bhi(v.y);
        a[4] += blo(v.z); a[5] += bhi(v.z);
        a[6] += blo(v.w); a[7] += bhi(v.w);
    }
    #pragma unroll
    for (int j = 0; j < 8; j++) red[t][j] = a[j];
    __syncthreads();
    for (int d = 16; d >= 1; d >>= 1) {
        if (rgrp < d) {
            #pragma unroll
            for (int j = 0; j < 8; j++) red[t][j] += red[t + d * 8][j];
        }
        __syncthreads();
    }
    if (rgrp == 0) {
        float inv = 1.0f / (float)max(end - beg, 1);
        #pragma unroll
        for (int j = 0; j < 8; j++)
            hg[g * HIDC + col0 + j] = red[t][j] * inv;
    }
}

// ---------------- readout ----------------
__global__ __launch_bounds__(256) void k_readout(const float* __restrict__ hg,
        const float* __restrict__ ppos, const float* __restrict__ pneg,
        const float* __restrict__ wfc, float* __restrict__ out) {
    __shared__ float red[256];
    __shared__ float ss[10];
    int t = threadIdx.x;
    int g = blockIdx.x;
    float hgv = hg[g * HIDC + t];
    for (int p = 0; p < 10; p++) {
        const float* P = (p < 5) ? (ppos + p * HIDC) : (pneg + (p - 5) * HIDC);
        float d = hgv - P[t];
        red[t] = d * d;
        __syncthreads();
        for (int s2 = 128; s2 > 0; s2 >>= 1) {
            if (t < s2) red[t] += red[t + s2];
            __syncthreads();
        }
        if (t == 0) {
            float dd = red[0];
            ss[p] = logf((dd + 1.0f) / (dd + EPSV));
        }
        __syncthreads();
    }
    if (t == 0) {
        float y = 0.f;
        #pragma unroll
        for (int p = 0; p < 10; p++) y += ss[p] * wfc[p];
        out[g] = 1.0f / (1.0f + expf(-y));
    }
}

extern "C" void kernel_launch(void* const* d_in, const int* in_sizes, int n_in,
                              void* d_out, int out_size, void* d_ws, size_t ws_size,
                              hipStream_t stream) {
    const float* h    = (const float*)d_in[0];
    const int*   src  = (const int*)d_in[1];
    const int*   dst  = (const int*)d_in[2];
    const int*   gid  = (const int*)d_in[3];
    const float* Wemb = (const float*)d_in[4];
    const float* bemb = (const float*)d_in[5];
    const float* Ws   = (const float*)d_in[6];
    const float* bs   = (const float*)d_in[7];
    const float* ppos = (const float*)d_in[8];
    const float* pneg = (const float*)d_in[9];
    const float* wfc  = (const float*)d_in[10];
    float* out = (float*)d_out;

    char* ws = (char*)d_ws;
    size_t off = 0;
    auto alloc = [&](size_t bytes) {
        void* p = ws + off;
        off += (bytes + 255) & ~(size_t)255;
        return p;
    };
    unsigned short* xb     = (unsigned short*)alloc((size_t)NPAD * HIDC * 2);  // bf16 row-major
    unsigned char*  xq     = (unsigned char*)alloc((size_t)NPAD * HIDC);       // fp8 shadow
    unsigned short* cb     = (unsigned short*)alloc((size_t)NPAD * HIDC * 2);  // bf16 row-major
    unsigned short* wsw    = (unsigned short*)alloc((size_t)(IN_DIMC * HIDC + N_LAYERSC * 2 * HIDC * HIDC) * 2);
    int*            offs   = (int*)alloc((size_t)(N_NODESC + 1) * 4);
    unsigned short* esrc   = (unsigned short*)alloc((size_t)N_EDGESC * 2);
    unsigned*       ebpack = (unsigned*)alloc((size_t)N_EDGESC * 4);
    int*            gbcnt  = (int*)alloc((size_t)NBUCK * 4);
    int*            boffB  = (int*)alloc((size_t)(NBUCK + 1) * 4);
    int*            gcurB  = (int*)alloc((size_t)NBUCK * 4);
    int*            gstart = (int*)alloc((size_t)(N_GRAPHSC + 1) * 4);
    float*          hg     = (float*)alloc((size_t)N_GRAPHSC * HIDC * 4);
    (void)ws_size; (void)in_sizes; (void)n_in; (void)out_size;

    hipMemsetAsync(gbcnt, 0, (size_t)NBUCK * 4, stream);

    const int WTOT = IN_DIMC * HIDC + N_LAYERSC * 2 * HIDC * HIDC; // 557056
    k_wconv<<<(WTOT + 255) / 256, 256, 0, stream>>>(Wemb, Ws, wsw);
    k_gbounds<<<1, 128, 0, stream>>>(gid, gstart);
    k_bcount<<<NBLK1, 256, 0, stream>>>(dst, gbcnt);
    k_bscan<<<1, 256, 0, stream>>>(gbcnt, boffB, gcurB);
    k_bscatter<<<NBLK1, 256, 0, stream>>>(src, dst, gcurB, ebpack);
    k_bbuild<<<NBUCK, 256, 0, stream>>>(ebpack, boffB, offs, esrc);

    k_egemm<<<NPAD / 32, 256, 0, stream>>>(h, wsw, bemb, xb, xq);

    for (int l = 0; l < N_LAYERSC; l++) {
        k_aggregate<<<(N_NODESC * 32 + 255) / 256, 256, 0, stream>>>(xq, offs, esrc, cb);
        k_lgemm<<<NPAD / 64, 256, 0, stream>>>(
            xb, cb,
            wsw + IN_DIMC * HIDC + (size_t)l * 2 * HIDC * HIDC,
            bs + (size_t)l * HIDC, xq);
    }
    k_pool<<<N_GRAPHSC * 4, 256, 0, stream>>>(xb, gstart, hg);
    k_readout<<<N_GRAPHSC, 256, 0, stream>>>(hg, ppos, pneg, wfc, out);
}